// Round 1
// baseline (752.290 us; speedup 1.0000x reference)
//
#include <hip/hip_runtime.h>
#include <hip/hip_bf16.h>
#include <math.h>

#define NPG   1024
#define KNN   16
#define IN_CH 64
#define OUT_CH 128
#define SPACE 4
#define PROP  64
#define NGRAPH 64
#define NTOT  (NGRAPH*NPG)   // 65536

// ---------------------------------------------------------------------------
// Kernel 1: s = x@Ws.T + bs ; h = x@Wh.T + bh   (thread per node)
// ---------------------------------------------------------------------------
__global__ __launch_bounds__(256) void k1_proj(
    const float* __restrict__ x, const float* __restrict__ Ws, const float* __restrict__ bs,
    const float* __restrict__ Wh, const float* __restrict__ bh,
    float* __restrict__ s_out, float* __restrict__ h_out)
{
    __shared__ float whl[PROP*IN_CH];   // [p][c]
    __shared__ float wsl[SPACE*IN_CH];  // [d][c]
    int tid = threadIdx.x;
    {
        const float4* src = (const float4*)Wh;
        float4* dst = (float4*)whl;
        for (int e = tid; e < PROP*IN_CH/4; e += 256) dst[e] = src[e];
        if (tid < SPACE*IN_CH/4) ((float4*)wsl)[tid] = ((const float4*)Ws)[tid];
    }
    __syncthreads();
    int i = blockIdx.x*256 + tid;

    float4 xr[16];
    const float4* xrow = (const float4*)(x + (size_t)i*IN_CH);
    #pragma unroll
    for (int q = 0; q < 16; q++) xr[q] = xrow[q];

    #pragma unroll
    for (int d = 0; d < SPACE; d++) {
        float acc = bs[d];
        const float4* wr = (const float4*)(wsl + d*IN_CH);
        #pragma unroll
        for (int q = 0; q < 16; q++) {
            float4 w = wr[q];
            acc += xr[q].x*w.x + xr[q].y*w.y + xr[q].z*w.z + xr[q].w*w.w;
        }
        s_out[(size_t)i*SPACE + d] = acc;
    }
    #pragma unroll 4
    for (int p = 0; p < PROP; p++) {
        float acc = bh[p];
        const float4* wr = (const float4*)(whl + p*IN_CH);
        #pragma unroll
        for (int q = 0; q < 16; q++) {
            float4 w = wr[q];
            acc += xr[q].x*w.x + xr[q].y*w.y + xr[q].z*w.z + xr[q].w*w.w;
        }
        h_out[(size_t)i*PROP + p] = acc;
    }
}

// ---------------------------------------------------------------------------
// Kernel 2: exact kNN (K=16) per graph + edge weights.
// One block = 256 queries of one graph; all 1024 graph points staged in LDS.
// d2 = |si|^2 + |sj|^2 - 2*dot  (matches reference formula); strict '<'
// replacement reproduces top_k tie-break (earlier index wins).
// ---------------------------------------------------------------------------
__global__ __launch_bounds__(256) void k2_knn(
    const float* __restrict__ s, int* __restrict__ idx_out, float* __restrict__ ew_out)
{
    __shared__ float4 s4[NPG];
    __shared__ float  sq[NPG];
    int tid = threadIdx.x;
    int g = blockIdx.x >> 2;
    int qbase = (blockIdx.x & 3) * 256;
    const float4* sg = (const float4*)(s + (size_t)g*NPG*SPACE);
    for (int e = tid; e < NPG; e += 256) {
        float4 v = sg[e];
        s4[e] = v;
        sq[e] = v.x*v.x + v.y*v.y + v.z*v.z + v.w*v.w;
    }
    __syncthreads();

    int qi = qbase + tid;
    float4 si = s4[qi];
    float sqi = sq[qi];

    float dk[KNN]; int ik[KNN];
    #pragma unroll
    for (int t = 0; t < KNN; t++) { dk[t] = INFINITY; ik[t] = 0; }
    float worst = INFINITY;

    for (int j = 0; j < NPG; j++) {
        float4 sj = s4[j];
        float dot = si.x*sj.x + si.y*sj.y + si.z*sj.z + si.w*sj.w;
        float d2 = sqi + sq[j] - 2.0f*dot;
        d2 = (j == qi) ? INFINITY : d2;
        if (d2 < worst) {
            bool done = false;
            #pragma unroll
            for (int t = 0; t < KNN; t++) {
                bool hit = (!done) && (dk[t] == worst);
                if (hit) { dk[t] = d2; ik[t] = j; done = true; }
            }
            worst = dk[0];
            #pragma unroll
            for (int t = 1; t < KNN; t++) worst = fmaxf(worst, dk[t]);
        }
    }

    size_t base = ((size_t)g*NPG + qi)*KNN;
    #pragma unroll
    for (int t = 0; t < KNN; t++) {
        int j = ik[t];
        float4 sj = s4[j];
        float dx = si.x-sj.x, dy = si.y-sj.y, dz = si.z-sj.z, dw = si.w-sj.w;
        float dd = dx*dx + dy*dy + dz*dz + dw*dw;
        ew_out[base+t] = expf(-10.0f*dd);
        idx_out[base+t] = g*NPG + j;       // global node id
    }
}

// ---------------------------------------------------------------------------
// Kernel 3: per-node aggregation (mean/max/smooth/deriv). Wave per node,
// lane = PROP channel. idx/ew/F broadcast via __shfl.
// ---------------------------------------------------------------------------
__global__ __launch_bounds__(256) void k3_agg(
    const float* __restrict__ h, const float* __restrict__ z,
    const int* __restrict__ idx, const float* __restrict__ ew,
    float* __restrict__ agg)
{
    int tid = threadIdx.x;
    int lane = tid & 63;
    int i = blockIdx.x*4 + (tid >> 6);
    float zi = z[i];

    int   kk = lane & 15;                         // duplicated per 16-group
    int   jv = idx[(size_t)i*KNN + kk];
    float ev = ew[(size_t)i*KNN + kk];
    float dz = z[jv] - zi;
    float ssum = fabsf(dz);
    ssum += __shfl_xor(ssum, 1);
    ssum += __shfl_xor(ssum, 2);
    ssum += __shfl_xor(ssum, 4);
    ssum += __shfl_xor(ssum, 8);
    float F = dz / (ssum + 1e-8f);

    float mean = 0.f, mx = -INFINITY, sm = 0.f, dv = 0.f;
    #pragma unroll
    for (int k = 0; k < KNN; k++) {
        int   j = __shfl(jv, k);
        float e = __shfl(ev, k);
        float f = __shfl(F,  k);
        float hv = h[(size_t)j*PROP + lane];      // coalesced 256B, L2-resident
        float m = hv * e;
        mean += m;
        mx = fmaxf(mx, m);
        sm += m * fabsf(f);
        dv += m * f;
    }
    size_t b = (size_t)i*256;
    agg[b       + lane] = mean * (1.f/16.f);
    agg[b +  64 + lane] = mx;
    agg[b + 128 + lane] = sm * (1.f/16.f);
    agg[b + 192 + lane] = dv;
}

// ---------------------------------------------------------------------------
// Kernel 4: out_pre = x@Wskip.T + agg@Wagg.T + bagg   (f32 register-blocked
// GEMM, A = [x | agg] virtual [N,320], B = [Wskip | Wagg] [128,320]).
// BM=64, BN=128, BK=64, 5 K-chunks. XOR-swizzled k-major LDS tiles.
// ---------------------------------------------------------------------------
__global__ __launch_bounds__(256) void k4_gemm(
    const float* __restrict__ x, const float* __restrict__ agg,
    const float* __restrict__ Wskip, const float* __restrict__ Wagg,
    const float* __restrict__ bagg, float* __restrict__ out)
{
    __shared__ float At[64*64];    // [k][m], m-index XOR-swizzled
    __shared__ float Bt[64*128];   // [k][o], o-index XOR-swizzled
    int tid = threadIdx.x;
    int tx = tid & 15, ty = tid >> 4;
    int mbase = blockIdx.x * 64;

    float acc[4][8];
    #pragma unroll
    for (int n = 0; n < 8; n++) {
        int o = (n < 4) ? (4*tx + n) : (64 + 4*tx + (n-4));
        float bv = bagg[o];
        #pragma unroll
        for (int m = 0; m < 4; m++) acc[m][n] = bv;
    }

    for (int ch = 0; ch < 5; ch++) {
        const float* asrc; int arl; int kb;
        const float* wsrc; int wrl;
        if (ch == 0) { asrc = x;   arl = 64;  kb = 0;          wsrc = Wskip; wrl = 64;  }
        else         { asrc = agg; arl = 256; kb = (ch-1)*64;  wsrc = Wagg;  wrl = 256; }

        #pragma unroll
        for (int it = 0; it < 4; it++) {          // stage A: 64x64
            int e = tid + it*256;
            int iL = e >> 4, kq = e & 15;
            float4 v = *(const float4*)(asrc + (size_t)(mbase+iL)*arl + kb + 4*kq);
            int col = iL ^ ((kq & 7) << 2);
            At[(4*kq+0)*64 + col] = v.x;
            At[(4*kq+1)*64 + col] = v.y;
            At[(4*kq+2)*64 + col] = v.z;
            At[(4*kq+3)*64 + col] = v.w;
        }
        #pragma unroll
        for (int it = 0; it < 8; it++) {          // stage B: 64x128
            int e = tid + it*256;
            int o = e >> 4, kq = e & 15;
            float4 v = *(const float4*)(wsrc + (size_t)o*wrl + kb + 4*kq);
            int col = o ^ ((kq & 7) << 2);
            Bt[(4*kq+0)*128 + col] = v.x;
            Bt[(4*kq+1)*128 + col] = v.y;
            Bt[(4*kq+2)*128 + col] = v.z;
            Bt[(4*kq+3)*128 + col] = v.w;
        }
        __syncthreads();

        #pragma unroll 4
        for (int k = 0; k < 64; k++) {
            int gk = ((k >> 2) & 7) << 2;
            float4 a  = *(const float4*)&At[k*64  + ((4*ty) ^ gk)];
            float4 b0 = *(const float4*)&Bt[k*128 + ((4*tx) ^ gk)];
            float4 b1 = *(const float4*)&Bt[k*128 + (64 + ((4*tx) ^ gk))];
            float am[4] = {a.x, a.y, a.z, a.w};
            float bn[8] = {b0.x, b0.y, b0.z, b0.w, b1.x, b1.y, b1.z, b1.w};
            #pragma unroll
            for (int m = 0; m < 4; m++)
                #pragma unroll
                for (int n = 0; n < 8; n++)
                    acc[m][n] += am[m] * bn[n];
        }
        __syncthreads();
    }

    #pragma unroll
    for (int m = 0; m < 4; m++) {
        int i = mbase + 4*ty + m;
        float4 o0 = make_float4(acc[m][0], acc[m][1], acc[m][2], acc[m][3]);
        float4 o1 = make_float4(acc[m][4], acc[m][5], acc[m][6], acc[m][7]);
        *(float4*)(out + (size_t)i*OUT_CH + 4*tx)      = o0;
        *(float4*)(out + (size_t)i*OUT_CH + 64 + 4*tx) = o1;
    }
}

// ---------------------------------------------------------------------------
// Kernel 5: per-channel sum / sumsq over N (atomic partial reduction)
// ---------------------------------------------------------------------------
__global__ __launch_bounds__(256) void k5_stats(
    const float* __restrict__ out, float* __restrict__ sums)
{
    int tid = threadIdx.x;
    int c = tid & 127;
    int half = tid >> 7;
    float s = 0.f, ss = 0.f;
    int rbase = blockIdx.x * 512 + half * 256;
    for (int rr = 0; rr < 256; rr++) {
        float v = out[(size_t)(rbase + rr)*OUT_CH + c];
        s  += v;
        ss += v*v;
    }
    atomicAdd(&sums[c], s);
    atomicAdd(&sums[128 + c], ss);
}

// ---------------------------------------------------------------------------
// Kernel 6: BatchNorm (training stats, biased var) + ReLU, in place on d_out
// ---------------------------------------------------------------------------
__global__ __launch_bounds__(256) void k6_bn(
    float* __restrict__ out, const float* __restrict__ sums,
    const float* __restrict__ gamma, const float* __restrict__ beta)
{
    int f = blockIdx.x*256 + threadIdx.x;     // float4 index
    float4 v = *(float4*)(out + (size_t)f*4);
    int o0 = (f*4) & 127;
    const float invN = 1.f / (float)NTOT;
    float r[4] = {v.x, v.y, v.z, v.w};
    #pragma unroll
    for (int c = 0; c < 4; c++) {
        int o = o0 + c;
        float mu  = sums[o] * invN;
        float var = sums[128+o] * invN - mu*mu;
        float sc  = gamma[o] * rsqrtf(var + 1e-5f);
        float sh  = beta[o] - mu*sc;
        float y = r[c]*sc + sh;
        r[c] = y > 0.f ? y : 0.f;
    }
    *(float4*)(out + (size_t)f*4) = make_float4(r[0], r[1], r[2], r[3]);
}

// ---------------------------------------------------------------------------
extern "C" void kernel_launch(void* const* d_in, const int* in_sizes, int n_in,
                              void* d_out, int out_size, void* d_ws, size_t ws_size,
                              hipStream_t stream)
{
    (void)in_sizes; (void)n_in; (void)out_size; (void)ws_size;
    const float* x     = (const float*)d_in[0];
    const float* z     = (const float*)d_in[1];
    /* d_in[2] = batch (int32) — graphs are fixed contiguous blocks, unused */
    const float* Ws    = (const float*)d_in[3];
    const float* bs    = (const float*)d_in[4];
    const float* Wh    = (const float*)d_in[5];
    const float* bh    = (const float*)d_in[6];
    const float* Wskip = (const float*)d_in[7];
    const float* Wagg  = (const float*)d_in[8];
    const float* bagg  = (const float*)d_in[9];
    const float* gamma = (const float*)d_in[10];
    const float* beta  = (const float*)d_in[11];
    float* out = (float*)d_out;

    const size_t N = NTOT;
    float* ws   = (float*)d_ws;
    float* agg  = ws;                        // N*256 f32
    float* sbuf = agg  + N*256;              // N*4
    float* hbuf = sbuf + N*4;                // N*64
    int*   idxb = (int*)(hbuf + N*64);       // N*16 int32
    float* ewb  = (float*)(idxb + N*16);     // N*16
    float* sums = ewb + N*16;                // 256  (sum | sumsq)

    hipMemsetAsync(sums, 0, 256*sizeof(float), stream);
    k1_proj<<<NTOT/256, 256, 0, stream>>>(x, Ws, bs, Wh, bh, sbuf, hbuf);
    k2_knn <<<NGRAPH*4, 256, 0, stream>>>(sbuf, idxb, ewb);
    k3_agg <<<NTOT/4,   256, 0, stream>>>(hbuf, z, idxb, ewb, agg);
    k4_gemm<<<NTOT/64,  256, 0, stream>>>(x, agg, Wskip, Wagg, bagg, out);
    k5_stats<<<NTOT/512, 256, 0, stream>>>(out, sums);
    k6_bn  <<<NTOT*OUT_CH/4/256, 256, 0, stream>>>(out, sums, gamma, beta);
}

// Round 2
// 411.134 us; speedup vs baseline: 1.8298x; 1.8298x over previous
//
#include <hip/hip_runtime.h>
#include <hip/hip_bf16.h>
#include <math.h>

#define NPG   1024
#define KNN   16
#define IN_CH 64
#define OUT_CH 128
#define SPACE 4
#define PROP  64
#define NGRAPH 64
#define NTOT  (NGRAPH*NPG)   // 65536

// key for +inf distance (monotonic-mapped +inf in high 32, dummy idx)
#define K_INF ((0xFF800000ULL << 32) | 0x3FFULL)

// ---------------------------------------------------------------------------
// Kernel 1: s = x@Ws.T + bs ; h = x@Wh.T + bh   (thread per node)
// ---------------------------------------------------------------------------
__global__ __launch_bounds__(256) void k1_proj(
    const float* __restrict__ x, const float* __restrict__ Ws, const float* __restrict__ bs,
    const float* __restrict__ Wh, const float* __restrict__ bh,
    float* __restrict__ s_out, float* __restrict__ h_out)
{
    __shared__ float whl[PROP*IN_CH];   // [p][c]
    __shared__ float wsl[SPACE*IN_CH];  // [d][c]
    int tid = threadIdx.x;
    {
        const float4* src = (const float4*)Wh;
        float4* dst = (float4*)whl;
        for (int e = tid; e < PROP*IN_CH/4; e += 256) dst[e] = src[e];
        if (tid < SPACE*IN_CH/4) ((float4*)wsl)[tid] = ((const float4*)Ws)[tid];
    }
    __syncthreads();
    int i = blockIdx.x*256 + tid;

    float4 xr[16];
    const float4* xrow = (const float4*)(x + (size_t)i*IN_CH);
    #pragma unroll
    for (int q = 0; q < 16; q++) xr[q] = xrow[q];

    #pragma unroll
    for (int d = 0; d < SPACE; d++) {
        float acc = bs[d];
        const float4* wr = (const float4*)(wsl + d*IN_CH);
        #pragma unroll
        for (int q = 0; q < 16; q++) {
            float4 w = wr[q];
            acc += xr[q].x*w.x + xr[q].y*w.y + xr[q].z*w.z + xr[q].w*w.w;
        }
        s_out[(size_t)i*SPACE + d] = acc;
    }
    #pragma unroll 4
    for (int p = 0; p < PROP; p++) {
        float acc = bh[p];
        const float4* wr = (const float4*)(whl + p*IN_CH);
        #pragma unroll
        for (int q = 0; q < 16; q++) {
            float4 w = wr[q];
            acc += xr[q].x*w.x + xr[q].y*w.y + xr[q].z*w.z + xr[q].w*w.w;
        }
        h_out[(size_t)i*PROP + p] = acc;
    }
}

// ---------------------------------------------------------------------------
// Kernel 2: exact kNN (K=16) per graph + edge weights.  v2:
//   - 4-way candidate split: lane = 4*grp + r; thread scans 256 candidates
//     (quarter r), so 4096 waves total = 4 waves/SIMD (vs 1 in v1).
//   - buffered-defer selection: cheap (d2<=worst) test + rare LDS append;
//     wave-synchronized flush does exact sorted insert of 64-bit keys
//     key = (monotonic_u32(d2) << 32) | j   (exact (d2, j) lex order).
//   - merge of the 4 per-quarter top-16s via 16 extraction steps with
//     2-stage __shfl_xor 64-bit min within each 4-lane group.
// ---------------------------------------------------------------------------
__global__ __launch_bounds__(256) void k2_knn(
    const float* __restrict__ s, int* __restrict__ idx_out, float* __restrict__ ew_out)
{
    __shared__ float4 s4[NPG];
    __shared__ float  sq[NPG];
    __shared__ unsigned short buf[256*16];
    int tid = threadIdx.x;
    int g    = blockIdx.x >> 4;            // graph
    int qblk = (blockIdx.x & 15) * 64;     // 64 queries per block
    const float4* sg = (const float4*)(s + (size_t)g*NPG*SPACE);
    for (int e = tid; e < NPG; e += 256) {
        float4 v = sg[e];
        s4[e] = v;
        sq[e] = v.x*v.x + v.y*v.y + v.z*v.z + v.w*v.w;
    }
    __syncthreads();

    int lane = tid & 63;
    int grp  = lane >> 2;                  // 16 queries per wave
    int r    = lane & 3;                   // candidate quarter
    int q    = qblk + (tid >> 6)*16 + grp; // query (within graph)
    float4 si = s4[q];
    float sqi = sq[q];

    unsigned long long kk[16];             // sorted ascending; kk[15] = worst
    #pragma unroll
    for (int t = 0; t < 16; t++) kk[t] = K_INF;
    float wf = INFINITY;                   // float value of current worst
    int cnt = 0;
    int bbase = tid * 16;

    auto flush = [&]() {
        #pragma unroll
        for (int b = 0; b < 16; ++b) {
            bool act = (b < cnt);
            int jb = act ? (int)buf[bbase + b] : 0;
            float4 sb = s4[jb];
            float dtb = si.x*sb.x + si.y*sb.y + si.z*sb.z + si.w*sb.w;
            float db = sqi + sq[jb] - 2.0f*dtb;
            unsigned int u = __float_as_uint(db);
            u = (u >> 31) ? ~u : (u | 0x80000000u);   // monotonic map
            unsigned long long nk = act
                ? (((unsigned long long)u << 32) | (unsigned int)jb)
                : ~0ULL;                               // > K_INF, no-op
            bool ct[16];
            #pragma unroll
            for (int t = 0; t < 16; t++) ct[t] = nk < kk[t];
            #pragma unroll
            for (int t = 15; t >= 1; t--)
                kk[t] = ct[t-1] ? kk[t-1] : (ct[t] ? nk : kk[t]);
            kk[0] = ct[0] ? nk : kk[0];
        }
        cnt = 0;
        unsigned int uw = (unsigned int)(kk[15] >> 32);
        wf = __uint_as_float((uw & 0x80000000u) ? (uw & 0x7FFFFFFFu) : ~uw);
    };

    #pragma unroll 1
    for (int it = 0; it < 256; ++it) {
        int j = r*256 + ((it + 2*r) & 255);    // bank-staggered per quarter
        float4 sj = s4[j];
        float dot = si.x*sj.x + si.y*sj.y + si.z*sj.z + si.w*sj.w;
        float d2 = sqi + sq[j] - 2.0f*dot;
        if ((d2 <= wf) && (j != q)) {
            buf[bbase + cnt] = (unsigned short)j;
            cnt++;
        }
        if (__any(cnt >= 16)) flush();
    }
    flush();                                    // drain remaining appends

    // ---- merge 4 quarter-top16s -> global top16 (16 extractions) ----
    size_t bq = ((size_t)(g*NPG + q)) * KNN;
    #pragma unroll
    for (int e = 0; e < 16; ++e) {
        unsigned long long mm = kk[0];
        unsigned long long o1 = __shfl_xor(mm, 1);
        mm = (o1 < mm) ? o1 : mm;
        unsigned long long o2 = __shfl_xor(mm, 2);
        mm = (o2 < mm) ? o2 : mm;
        if (r == (e & 3)) {                     // one lane outputs this rank
            int j = (int)(mm & 0xFFFFFFFFULL);
            float4 sj = s4[j];
            float dx = si.x-sj.x, dy = si.y-sj.y, dz = si.z-sj.z, dw = si.w-sj.w;
            float dd = dx*dx + dy*dy + dz*dz + dw*dw;
            ew_out[bq + e] = expf(-10.0f*dd);
            idx_out[bq + e] = g*NPG + j;        // global node id
        }
        bool rem = (kk[0] == mm);               // keys unique (contain j)
        #pragma unroll
        for (int t = 0; t < 15; ++t) kk[t] = rem ? kk[t+1] : kk[t];
        kk[15] = rem ? K_INF : kk[15];
    }
}

// ---------------------------------------------------------------------------
// Kernel 3: per-node aggregation (mean/max/smooth/deriv). Wave per node,
// lane = PROP channel. idx/ew/F broadcast via __shfl.
// ---------------------------------------------------------------------------
__global__ __launch_bounds__(256) void k3_agg(
    const float* __restrict__ h, const float* __restrict__ z,
    const int* __restrict__ idx, const float* __restrict__ ew,
    float* __restrict__ agg)
{
    int tid = threadIdx.x;
    int lane = tid & 63;
    int i = blockIdx.x*4 + (tid >> 6);
    float zi = z[i];

    int   kk = lane & 15;                         // duplicated per 16-group
    int   jv = idx[(size_t)i*KNN + kk];
    float ev = ew[(size_t)i*KNN + kk];
    float dz = z[jv] - zi;
    float ssum = fabsf(dz);
    ssum += __shfl_xor(ssum, 1);
    ssum += __shfl_xor(ssum, 2);
    ssum += __shfl_xor(ssum, 4);
    ssum += __shfl_xor(ssum, 8);
    float F = dz / (ssum + 1e-8f);

    float mean = 0.f, mx = -INFINITY, sm = 0.f, dv = 0.f;
    #pragma unroll
    for (int k = 0; k < KNN; k++) {
        int   j = __shfl(jv, k);
        float e = __shfl(ev, k);
        float f = __shfl(F,  k);
        float hv = h[(size_t)j*PROP + lane];      // coalesced 256B, L2-resident
        float m = hv * e;
        mean += m;
        mx = fmaxf(mx, m);
        sm += m * fabsf(f);
        dv += m * f;
    }
    size_t b = (size_t)i*256;
    agg[b       + lane] = mean * (1.f/16.f);
    agg[b +  64 + lane] = mx;
    agg[b + 128 + lane] = sm * (1.f/16.f);
    agg[b + 192 + lane] = dv;
}

// ---------------------------------------------------------------------------
// Kernel 4: out_pre = x@Wskip.T + agg@Wagg.T + bagg   (f32 register-blocked
// GEMM, A = [x | agg] virtual [N,320], B = [Wskip | Wagg] [128,320]).
// BM=64, BN=128, BK=64, 5 K-chunks. XOR-swizzled k-major LDS tiles.
// ---------------------------------------------------------------------------
__global__ __launch_bounds__(256) void k4_gemm(
    const float* __restrict__ x, const float* __restrict__ agg,
    const float* __restrict__ Wskip, const float* __restrict__ Wagg,
    const float* __restrict__ bagg, float* __restrict__ out)
{
    __shared__ float At[64*64];    // [k][m], m-index XOR-swizzled
    __shared__ float Bt[64*128];   // [k][o], o-index XOR-swizzled
    int tid = threadIdx.x;
    int tx = tid & 15, ty = tid >> 4;
    int mbase = blockIdx.x * 64;

    float acc[4][8];
    #pragma unroll
    for (int n = 0; n < 8; n++) {
        int o = (n < 4) ? (4*tx + n) : (64 + 4*tx + (n-4));
        float bv = bagg[o];
        #pragma unroll
        for (int m = 0; m < 4; m++) acc[m][n] = bv;
    }

    for (int ch = 0; ch < 5; ch++) {
        const float* asrc; int arl; int kb;
        const float* wsrc; int wrl;
        if (ch == 0) { asrc = x;   arl = 64;  kb = 0;          wsrc = Wskip; wrl = 64;  }
        else         { asrc = agg; arl = 256; kb = (ch-1)*64;  wsrc = Wagg;  wrl = 256; }

        #pragma unroll
        for (int it = 0; it < 4; it++) {          // stage A: 64x64
            int e = tid + it*256;
            int iL = e >> 4, kq = e & 15;
            float4 v = *(const float4*)(asrc + (size_t)(mbase+iL)*arl + kb + 4*kq);
            int col = iL ^ ((kq & 7) << 2);
            At[(4*kq+0)*64 + col] = v.x;
            At[(4*kq+1)*64 + col] = v.y;
            At[(4*kq+2)*64 + col] = v.z;
            At[(4*kq+3)*64 + col] = v.w;
        }
        #pragma unroll
        for (int it = 0; it < 8; it++) {          // stage B: 64x128
            int e = tid + it*256;
            int o = e >> 4, kq = e & 15;
            float4 v = *(const float4*)(wsrc + (size_t)o*wrl + kb + 4*kq);
            int col = o ^ ((kq & 7) << 2);
            Bt[(4*kq+0)*128 + col] = v.x;
            Bt[(4*kq+1)*128 + col] = v.y;
            Bt[(4*kq+2)*128 + col] = v.z;
            Bt[(4*kq+3)*128 + col] = v.w;
        }
        __syncthreads();

        #pragma unroll 4
        for (int k = 0; k < 64; k++) {
            int gk = ((k >> 2) & 7) << 2;
            float4 a  = *(const float4*)&At[k*64  + ((4*ty) ^ gk)];
            float4 b0 = *(const float4*)&Bt[k*128 + ((4*tx) ^ gk)];
            float4 b1 = *(const float4*)&Bt[k*128 + (64 + ((4*tx) ^ gk))];
            float am[4] = {a.x, a.y, a.z, a.w};
            float bn[8] = {b0.x, b0.y, b0.z, b0.w, b1.x, b1.y, b1.z, b1.w};
            #pragma unroll
            for (int m = 0; m < 4; m++)
                #pragma unroll
                for (int n = 0; n < 8; n++)
                    acc[m][n] += am[m] * bn[n];
        }
        __syncthreads();
    }

    #pragma unroll
    for (int m = 0; m < 4; m++) {
        int i = mbase + 4*ty + m;
        float4 o0 = make_float4(acc[m][0], acc[m][1], acc[m][2], acc[m][3]);
        float4 o1 = make_float4(acc[m][4], acc[m][5], acc[m][6], acc[m][7]);
        *(float4*)(out + (size_t)i*OUT_CH + 4*tx)      = o0;
        *(float4*)(out + (size_t)i*OUT_CH + 64 + 4*tx) = o1;
    }
}

// ---------------------------------------------------------------------------
// Kernel 5: per-channel sum / sumsq over N (atomic partial reduction)
// ---------------------------------------------------------------------------
__global__ __launch_bounds__(256) void k5_stats(
    const float* __restrict__ out, float* __restrict__ sums)
{
    int tid = threadIdx.x;
    int c = tid & 127;
    int half = tid >> 7;
    float s = 0.f, ss = 0.f;
    int rbase = blockIdx.x * 512 + half * 256;
    for (int rr = 0; rr < 256; rr++) {
        float v = out[(size_t)(rbase + rr)*OUT_CH + c];
        s  += v;
        ss += v*v;
    }
    atomicAdd(&sums[c], s);
    atomicAdd(&sums[128 + c], ss);
}

// ---------------------------------------------------------------------------
// Kernel 6: BatchNorm (training stats, biased var) + ReLU, in place on d_out
// ---------------------------------------------------------------------------
__global__ __launch_bounds__(256) void k6_bn(
    float* __restrict__ out, const float* __restrict__ sums,
    const float* __restrict__ gamma, const float* __restrict__ beta)
{
    int f = blockIdx.x*256 + threadIdx.x;     // float4 index
    float4 v = *(float4*)(out + (size_t)f*4);
    int o0 = (f*4) & 127;
    const float invN = 1.f / (float)NTOT;
    float r[4] = {v.x, v.y, v.z, v.w};
    #pragma unroll
    for (int c = 0; c < 4; c++) {
        int o = o0 + c;
        float mu  = sums[o] * invN;
        float var = sums[128+o] * invN - mu*mu;
        float sc  = gamma[o] * rsqrtf(var + 1e-5f);
        float sh  = beta[o] - mu*sc;
        float y = r[c]*sc + sh;
        r[c] = y > 0.f ? y : 0.f;
    }
    *(float4*)(out + (size_t)f*4) = make_float4(r[0], r[1], r[2], r[3]);
}

// ---------------------------------------------------------------------------
extern "C" void kernel_launch(void* const* d_in, const int* in_sizes, int n_in,
                              void* d_out, int out_size, void* d_ws, size_t ws_size,
                              hipStream_t stream)
{
    (void)in_sizes; (void)n_in; (void)out_size; (void)ws_size;
    const float* x     = (const float*)d_in[0];
    const float* z     = (const float*)d_in[1];
    /* d_in[2] = batch (int32) — graphs are fixed contiguous blocks, unused */
    const float* Ws    = (const float*)d_in[3];
    const float* bs    = (const float*)d_in[4];
    const float* Wh    = (const float*)d_in[5];
    const float* bh    = (const float*)d_in[6];
    const float* Wskip = (const float*)d_in[7];
    const float* Wagg  = (const float*)d_in[8];
    const float* bagg  = (const float*)d_in[9];
    const float* gamma = (const float*)d_in[10];
    const float* beta  = (const float*)d_in[11];
    float* out = (float*)d_out;

    const size_t N = NTOT;
    float* ws   = (float*)d_ws;
    float* agg  = ws;                        // N*256 f32
    float* sbuf = agg  + N*256;              // N*4
    float* hbuf = sbuf + N*4;                // N*64
    int*   idxb = (int*)(hbuf + N*64);       // N*16 int32
    float* ewb  = (float*)(idxb + N*16);     // N*16
    float* sums = ewb + N*16;                // 256  (sum | sumsq)

    hipMemsetAsync(sums, 0, 256*sizeof(float), stream);
    k1_proj<<<NTOT/256, 256, 0, stream>>>(x, Ws, bs, Wh, bh, sbuf, hbuf);
    k2_knn <<<NGRAPH*16, 256, 0, stream>>>(sbuf, idxb, ewb);
    k3_agg <<<NTOT/4,   256, 0, stream>>>(hbuf, z, idxb, ewb, agg);
    k4_gemm<<<NTOT/64,  256, 0, stream>>>(x, agg, Wskip, Wagg, bagg, out);
    k5_stats<<<NTOT/512, 256, 0, stream>>>(out, sums);
    k6_bn  <<<NTOT*OUT_CH/4/256, 256, 0, stream>>>(out, sums, gamma, beta);
}

// Round 3
// 333.713 us; speedup vs baseline: 2.2543x; 1.2320x over previous
//
#include <hip/hip_runtime.h>
#include <hip/hip_bf16.h>
#include <math.h>

#define NPG   1024
#define KNN   16
#define IN_CH 64
#define OUT_CH 128
#define SPACE 4
#define PROP  64
#define NGRAPH 64
#define NTOT  (NGRAPH*NPG)   // 65536

typedef unsigned long long u64;
typedef unsigned int u32;

// key for +inf distance (monotonic-mapped +inf in high 32, dummy idx)
#define K_INF ((0xFF800000ULL << 32) | 0x3FFULL)

// ---------------------------------------------------------------------------
// Kernel 1: s = x@Ws.T + bs ; h = x@Wh.T + bh   (thread per node)
// ---------------------------------------------------------------------------
__global__ __launch_bounds__(256) void k1_proj(
    const float* __restrict__ x, const float* __restrict__ Ws, const float* __restrict__ bs,
    const float* __restrict__ Wh, const float* __restrict__ bh,
    float* __restrict__ s_out, float* __restrict__ h_out)
{
    __shared__ float whl[PROP*IN_CH];   // [p][c]
    __shared__ float wsl[SPACE*IN_CH];  // [d][c]
    int tid = threadIdx.x;
    {
        const float4* src = (const float4*)Wh;
        float4* dst = (float4*)whl;
        for (int e = tid; e < PROP*IN_CH/4; e += 256) dst[e] = src[e];
        if (tid < SPACE*IN_CH/4) ((float4*)wsl)[tid] = ((const float4*)Ws)[tid];
    }
    __syncthreads();
    int i = blockIdx.x*256 + tid;

    float4 xr[16];
    const float4* xrow = (const float4*)(x + (size_t)i*IN_CH);
    #pragma unroll
    for (int q = 0; q < 16; q++) xr[q] = xrow[q];

    #pragma unroll
    for (int d = 0; d < SPACE; d++) {
        float acc = bs[d];
        const float4* wr = (const float4*)(wsl + d*IN_CH);
        #pragma unroll
        for (int q = 0; q < 16; q++) {
            float4 w = wr[q];
            acc += xr[q].x*w.x + xr[q].y*w.y + xr[q].z*w.z + xr[q].w*w.w;
        }
        s_out[(size_t)i*SPACE + d] = acc;
    }
    #pragma unroll 4
    for (int p = 0; p < PROP; p++) {
        float acc = bh[p];
        const float4* wr = (const float4*)(whl + p*IN_CH);
        #pragma unroll
        for (int q = 0; q < 16; q++) {
            float4 w = wr[q];
            acc += xr[q].x*w.x + xr[q].y*w.y + xr[q].z*w.z + xr[q].w*w.w;
        }
        h_out[(size_t)i*PROP + p] = acc;
    }
}

// ---------------------------------------------------------------------------
// Bitonic compare-exchange helpers on u64 (LITERAL indices via macros only —
// rule #20: no runtime-indexed register arrays).
// ---------------------------------------------------------------------------
__device__ __forceinline__ void ce_up(u64& a, u64& b) {
    u64 lo = a < b ? a : b; u64 hi = a < b ? b : a; a = lo; b = hi;
}
__device__ __forceinline__ void ce_dn(u64& a, u64& b) {
    u64 lo = a < b ? a : b; u64 hi = a < b ? b : a; a = hi; b = lo;
}
// full bitonic sort of 16 (ascending), 80 CE
#define S16(n) do{ \
 ce_up(n[0],n[1]); ce_dn(n[2],n[3]); ce_up(n[4],n[5]); ce_dn(n[6],n[7]); ce_up(n[8],n[9]); ce_dn(n[10],n[11]); ce_up(n[12],n[13]); ce_dn(n[14],n[15]); \
 ce_up(n[0],n[2]); ce_up(n[1],n[3]); ce_dn(n[4],n[6]); ce_dn(n[5],n[7]); ce_up(n[8],n[10]); ce_up(n[9],n[11]); ce_dn(n[12],n[14]); ce_dn(n[13],n[15]); \
 ce_up(n[0],n[1]); ce_up(n[2],n[3]); ce_dn(n[4],n[5]); ce_dn(n[6],n[7]); ce_up(n[8],n[9]); ce_up(n[10],n[11]); ce_dn(n[12],n[13]); ce_dn(n[14],n[15]); \
 ce_up(n[0],n[4]); ce_up(n[1],n[5]); ce_up(n[2],n[6]); ce_up(n[3],n[7]); ce_dn(n[8],n[12]); ce_dn(n[9],n[13]); ce_dn(n[10],n[14]); ce_dn(n[11],n[15]); \
 ce_up(n[0],n[2]); ce_up(n[1],n[3]); ce_up(n[4],n[6]); ce_up(n[5],n[7]); ce_dn(n[8],n[10]); ce_dn(n[9],n[11]); ce_dn(n[12],n[14]); ce_dn(n[13],n[15]); \
 ce_up(n[0],n[1]); ce_up(n[2],n[3]); ce_dn(n[4],n[5]); ce_dn(n[6],n[7]); ce_up(n[8],n[9]); ce_up(n[10],n[11]); ce_dn(n[12],n[13]); ce_dn(n[14],n[15]); \
 M16(n); \
}while(0)
// bitonic merge of 16 (input bitonic -> ascending), 32 CE
#define M16(n) do{ \
 ce_up(n[0],n[8]); ce_up(n[1],n[9]); ce_up(n[2],n[10]); ce_up(n[3],n[11]); ce_up(n[4],n[12]); ce_up(n[5],n[13]); ce_up(n[6],n[14]); ce_up(n[7],n[15]); \
 ce_up(n[0],n[4]); ce_up(n[1],n[5]); ce_up(n[2],n[6]); ce_up(n[3],n[7]); ce_up(n[8],n[12]); ce_up(n[9],n[13]); ce_up(n[10],n[14]); ce_up(n[11],n[15]); \
 ce_up(n[0],n[2]); ce_up(n[1],n[3]); ce_up(n[4],n[6]); ce_up(n[5],n[7]); ce_up(n[8],n[10]); ce_up(n[9],n[11]); ce_up(n[12],n[14]); ce_up(n[13],n[15]); \
 ce_up(n[0],n[1]); ce_up(n[2],n[3]); ce_up(n[4],n[5]); ce_up(n[6],n[7]); ce_up(n[8],n[9]); ce_up(n[10],n[11]); ce_up(n[12],n[13]); ce_up(n[14],n[15]); \
}while(0)

__device__ __forceinline__ float unmono(u32 uw) {
    return __uint_as_float((uw & 0x80000000u) ? (uw & 0x7FFFFFFFu) : ~uw);
}

// ---------------------------------------------------------------------------
// Kernel 2 v3: exact kNN (K=16) per graph + edge weights.
//   - lane = 4*query_grp + quarter; thread scans 256 candidates.
//   - cheap (d2<=worst) filter; accepted j's packed into a 192-bit register
//     queue (3x u64, 10 bits each) -- NO LDS appends.
//   - wave-synchronized flush: re-derive d2 from LDS, bitonic sort-16 +
//     reversed-min half-cleaner + bitonic merge into sorted top-16 keys
//     key = (monotonic_u32(d2)<<32) | j  (exact (d2, j) lex order).
//   - cross-quarter merge: 2 rounds of u64 shfl_xor reversed-min + merge.
// ---------------------------------------------------------------------------
__global__ __launch_bounds__(256, 4) void k2_knn(
    const float* __restrict__ s, int* __restrict__ idx_out, float* __restrict__ ew_out)
{
    __shared__ float4 s4[NPG];
    int tid = threadIdx.x;
    int g    = blockIdx.x >> 4;            // graph
    int qblk = (blockIdx.x & 15) * 64;     // 64 queries per block
    const float4* sg = (const float4*)(s + (size_t)g*NPG*SPACE);
    for (int e = tid; e < NPG; e += 256) s4[e] = sg[e];
    __syncthreads();

    int lane = tid & 63;
    int grp  = lane >> 2;                  // 16 queries per wave
    int r    = lane & 3;                   // candidate quarter
    int q    = qblk + (tid >> 6)*16 + grp; // query (within graph)
    float4 si = s4[q];

    u64 kk[16];                            // sorted ascending; kk[15] = worst
    #pragma unroll
    for (int t = 0; t < 16; t++) kk[t] = K_INF;
    float wf = INFINITY;
    int cnt = 0;
    u64 q0 = 0, q1 = 0, q2 = 0;            // packed accept queue (16 x 10b)

    auto flush = [&]() {
        u64 nn[16];
        #pragma unroll
        for (int b = 0; b < 16; ++b) {
            int jb = (int)(q0 & 1023u);
            q0 = (q0 >> 10) | (q1 << 54);
            q1 = (q1 >> 10) | (q2 << 54);
            q2 = q2 >> 10;
            bool act = (b < cnt);
            float4 sb = s4[jb];
            float dx = si.x-sb.x, dy = si.y-sb.y, dz = si.z-sb.z, dw = si.w-sb.w;
            float db = dx*dx + dy*dy + dz*dz + dw*dw;
            u32 u = __float_as_uint(db);
            u = (u >> 31) ? ~u : (u | 0x80000000u);
            nn[b] = act ? ((((u64)u) << 32) | (u32)jb) : ~0ULL;
        }
        S16(nn);
        // reverse nn in place, then half-cleaner vs kk, then merge
        #pragma unroll
        for (int t = 0; t < 8; ++t) { u64 tmp = nn[t]; nn[t] = nn[15-t]; nn[15-t] = tmp; }
        #pragma unroll
        for (int t = 0; t < 16; ++t) { u64 a = kk[t]; u64 b = nn[t]; nn[t] = a < b ? a : b; }
        M16(nn);
        #pragma unroll
        for (int t = 0; t < 16; ++t) kk[t] = nn[t];
        cnt = 0;
        wf = unmono((u32)(kk[15] >> 32));
    };

    #pragma unroll 1
    for (int it = 0; it < 256; ++it) {
        int j = r*256 + ((it + 61*r) & 255);   // bank-staggered per quarter
        float4 sj = s4[j];
        float dx = si.x-sj.x, dy = si.y-sj.y, dz = si.z-sj.z, dw = si.w-sj.w;
        float d2 = dx*dx + dy*dy + dz*dz + dw*dw;
        if ((d2 <= wf) && (j != q)) {
            q2 = (q2 << 10) | (q1 >> 54);
            q1 = (q1 << 10) | (q0 >> 54);
            q0 = (q0 << 10) | (u32)j;
            cnt++;
        }
        if (__any(cnt >= 16)) flush();
    }
    if (__any(cnt > 0)) flush();

    // ---- merge 4 quarter-top16s (lanes r=0..3 of each group) ----
    #pragma unroll
    for (int m = 1; m <= 2; m <<= 1) {
        u64 pp[16];
        #pragma unroll
        for (int t = 0; t < 16; ++t)
            pp[t] = (u64)__shfl_xor((long long)kk[15-t], m);
        #pragma unroll
        for (int t = 0; t < 16; ++t) { u64 a = kk[t]; u64 b = pp[t]; kk[t] = a < b ? a : b; }
        M16(kk);
    }

    // ---- output: all 4 lanes hold the global sorted top-16; split writes ----
    size_t bq = ((size_t)(g*NPG + q)) * KNN;
    #pragma unroll
    for (int e = 0; e < 16; ++e) {
        if ((e & 3) == r) {
            u64 key = kk[e];
            int j = (int)(key & 1023u);
            float d2 = unmono((u32)(key >> 32));
            ew_out[bq + e] = expf(-10.0f * d2);
            idx_out[bq + e] = g*NPG + j;
        }
    }
}

// ---------------------------------------------------------------------------
// Kernel 3: per-node aggregation (mean/max/smooth/deriv). Wave per node,
// lane = PROP channel. idx/ew/F broadcast via __shfl.
// ---------------------------------------------------------------------------
__global__ __launch_bounds__(256) void k3_agg(
    const float* __restrict__ h, const float* __restrict__ z,
    const int* __restrict__ idx, const float* __restrict__ ew,
    float* __restrict__ agg)
{
    int tid = threadIdx.x;
    int lane = tid & 63;
    int i = blockIdx.x*4 + (tid >> 6);
    float zi = z[i];

    int   kk = lane & 15;                         // duplicated per 16-group
    int   jv = idx[(size_t)i*KNN + kk];
    float ev = ew[(size_t)i*KNN + kk];
    float dz = z[jv] - zi;
    float ssum = fabsf(dz);
    ssum += __shfl_xor(ssum, 1);
    ssum += __shfl_xor(ssum, 2);
    ssum += __shfl_xor(ssum, 4);
    ssum += __shfl_xor(ssum, 8);
    float F = dz / (ssum + 1e-8f);

    float mean = 0.f, mx = -INFINITY, sm = 0.f, dv = 0.f;
    #pragma unroll
    for (int k = 0; k < KNN; k++) {
        int   j = __shfl(jv, k);
        float e = __shfl(ev, k);
        float f = __shfl(F,  k);
        float hv = h[(size_t)j*PROP + lane];      // coalesced 256B, L2-resident
        float m = hv * e;
        mean += m;
        mx = fmaxf(mx, m);
        sm += m * fabsf(f);
        dv += m * f;
    }
    size_t b = (size_t)i*256;
    agg[b       + lane] = mean * (1.f/16.f);
    agg[b +  64 + lane] = mx;
    agg[b + 128 + lane] = sm * (1.f/16.f);
    agg[b + 192 + lane] = dv;
}

// ---------------------------------------------------------------------------
// Kernel 4 v2: out_pre = x@Wskip.T + agg@Wagg.T + bagg via bf16 MFMA
// (16x16x32, f32 accum). A = [x | agg] virtual [N,320]; B = [Wskip|Wagg].
// Block: 64 rows x 128 cols, 4 waves (2 row-halves x 2 col-halves),
// 5 K-chunks of 64. f32->bf16 RNE fused into XOR-swizzled LDS staging.
// Fused BN-stats epilogue (was k5): per-channel sum/sumsq -> atomicAdd.
// ---------------------------------------------------------------------------
typedef __attribute__((ext_vector_type(8))) short bf16x8;
typedef __attribute__((ext_vector_type(4))) float f32x4;

__device__ __forceinline__ u32 pk2bf(float a, float b) {
    u32 ua = __float_as_uint(a);
    u32 ub = __float_as_uint(b);
    ua = (ua + 0x7fffu + ((ua >> 16) & 1u)) >> 16;
    ub = (ub + 0x7fffu + ((ub >> 16) & 1u)) >> 16;
    return (ua & 0xffffu) | (ub << 16);
}

__global__ __launch_bounds__(256, 4) void k4_gemm(
    const float* __restrict__ x, const float* __restrict__ agg,
    const float* __restrict__ Wskip, const float* __restrict__ Wagg,
    const float* __restrict__ bagg, float* __restrict__ out,
    float* __restrict__ sums)
{
    __shared__ char Al[64*128];    // [row][k] bf16, 128B rows, XOR-swizzled
    __shared__ char Bl[128*128];   // [n][k]   bf16, 128B rows, XOR-swizzled
    __shared__ float st[OUT_CH], st2[OUT_CH];
    int tid = threadIdx.x;
    int lane = tid & 63, wid = tid >> 6;
    int wy = wid >> 1, wx = wid & 1;
    int mbase = blockIdx.x * 64;

    if (tid < OUT_CH) { st[tid] = 0.f; st2[tid] = 0.f; }

    int colb = wx*64 + (lane & 15);
    f32x4 acc[2][4];
    #pragma unroll
    for (int nc = 0; nc < 4; ++nc) {
        float bv = bagg[colb + nc*16];
        #pragma unroll
        for (int mr = 0; mr < 2; ++mr) acc[mr][nc] = (f32x4){bv, bv, bv, bv};
    }

    int arow = tid >> 2, akq = (tid & 3) * 16;     // A: 16 elems/thread
    int brow = tid >> 1, bkq = (tid & 1) * 32;     // B: 32 elems/thread
    int asw = (arow & 7) << 4, bsw = (brow & 7) << 4;

    for (int ch = 0; ch < 5; ++ch) {
        const float* ap = (ch == 0) ? (x   + (size_t)(mbase + arow)*64  + akq)
                                    : (agg + (size_t)(mbase + arow)*256 + (ch-1)*64 + akq);
        const float* bp = (ch == 0) ? (Wskip + (size_t)brow*64  + bkq)
                                    : (Wagg  + (size_t)brow*256 + (ch-1)*64 + bkq);
        __syncthreads();   // previous chunk's reads done before overwrite
        {
            float4 f0 = ((const float4*)ap)[0], f1 = ((const float4*)ap)[1];
            float4 f2 = ((const float4*)ap)[2], f3 = ((const float4*)ap)[3];
            uint4 u0 = { pk2bf(f0.x,f0.y), pk2bf(f0.z,f0.w), pk2bf(f1.x,f1.y), pk2bf(f1.z,f1.w) };
            uint4 u1 = { pk2bf(f2.x,f2.y), pk2bf(f2.z,f2.w), pk2bf(f3.x,f3.y), pk2bf(f3.z,f3.w) };
            *(uint4*)(Al + arow*128 + ((akq*2     ) ^ asw)) = u0;
            *(uint4*)(Al + arow*128 + ((akq*2 + 16) ^ asw)) = u1;
        }
        #pragma unroll
        for (int g2 = 0; g2 < 4; ++g2) {
            float4 f0 = ((const float4*)bp)[2*g2], f1 = ((const float4*)bp)[2*g2+1];
            uint4 u = { pk2bf(f0.x,f0.y), pk2bf(f0.z,f0.w), pk2bf(f1.x,f1.y), pk2bf(f1.z,f1.w) };
            *(uint4*)(Bl + brow*128 + ((bkq*2 + g2*16) ^ bsw)) = u;
        }
        __syncthreads();
        #pragma unroll
        for (int ks = 0; ks < 2; ++ks) {
            int kb = ks*64 + ((lane >> 4) * 16);
            bf16x8 af[2], bfr[4];
            #pragma unroll
            for (int mr = 0; mr < 2; ++mr) {
                int row = wy*32 + mr*16 + (lane & 15);
                af[mr] = *(const bf16x8*)(Al + row*128 + (kb ^ ((row & 7) << 4)));
            }
            #pragma unroll
            for (int nc = 0; nc < 4; ++nc) {
                int n = wx*64 + nc*16 + (lane & 15);
                bfr[nc] = *(const bf16x8*)(Bl + n*128 + (kb ^ ((n & 7) << 4)));
            }
            #pragma unroll
            for (int mr = 0; mr < 2; ++mr)
                #pragma unroll
                for (int nc = 0; nc < 4; ++nc)
                    acc[mr][nc] = __builtin_amdgcn_mfma_f32_16x16x32_bf16(
                        af[mr], bfr[nc], acc[mr][nc], 0, 0, 0);
        }
    }

    // ---- epilogue: store + per-channel BN partial stats ----
    float s1[4] = {0,0,0,0}, s2[4] = {0,0,0,0};
    #pragma unroll
    for (int mr = 0; mr < 2; ++mr) {
        int r0 = mbase + wy*32 + mr*16 + (lane >> 4)*4;
        #pragma unroll
        for (int nc = 0; nc < 4; ++nc) {
            int c = colb + nc*16;
            #pragma unroll
            for (int j = 0; j < 4; ++j) {
                float v = acc[mr][nc][j];
                out[(size_t)(r0 + j)*OUT_CH + c] = v;
                s1[nc] += v;
                s2[nc] += v*v;
            }
        }
    }
    #pragma unroll
    for (int nc = 0; nc < 4; ++nc) {
        s1[nc] += __shfl_xor(s1[nc], 16); s1[nc] += __shfl_xor(s1[nc], 32);
        s2[nc] += __shfl_xor(s2[nc], 16); s2[nc] += __shfl_xor(s2[nc], 32);
    }
    __syncthreads();
    if ((lane >> 4) == 0) {
        #pragma unroll
        for (int nc = 0; nc < 4; ++nc) {
            atomicAdd(&st[colb + nc*16],  s1[nc]);
            atomicAdd(&st2[colb + nc*16], s2[nc]);
        }
    }
    __syncthreads();
    if (tid < OUT_CH) {
        atomicAdd(&sums[tid], st[tid]);
        atomicAdd(&sums[OUT_CH + tid], st2[tid]);
    }
}

// ---------------------------------------------------------------------------
// Kernel 6: BatchNorm (training stats, biased var) + ReLU, in place on d_out
// ---------------------------------------------------------------------------
__global__ __launch_bounds__(256) void k6_bn(
    float* __restrict__ out, const float* __restrict__ sums,
    const float* __restrict__ gamma, const float* __restrict__ beta)
{
    int f = blockIdx.x*256 + threadIdx.x;     // float4 index
    float4 v = *(float4*)(out + (size_t)f*4);
    int o0 = (f*4) & 127;
    const float invN = 1.f / (float)NTOT;
    float r[4] = {v.x, v.y, v.z, v.w};
    #pragma unroll
    for (int c = 0; c < 4; c++) {
        int o = o0 + c;
        float mu  = sums[o] * invN;
        float var = sums[128+o] * invN - mu*mu;
        float sc  = gamma[o] * rsqrtf(var + 1e-5f);
        float sh  = beta[o] - mu*sc;
        float y = r[c]*sc + sh;
        r[c] = y > 0.f ? y : 0.f;
    }
    *(float4*)(out + (size_t)f*4) = make_float4(r[0], r[1], r[2], r[3]);
}

// ---------------------------------------------------------------------------
extern "C" void kernel_launch(void* const* d_in, const int* in_sizes, int n_in,
                              void* d_out, int out_size, void* d_ws, size_t ws_size,
                              hipStream_t stream)
{
    (void)in_sizes; (void)n_in; (void)out_size; (void)ws_size;
    const float* x     = (const float*)d_in[0];
    const float* z     = (const float*)d_in[1];
    /* d_in[2] = batch (int32) — graphs are fixed contiguous blocks, unused */
    const float* Ws    = (const float*)d_in[3];
    const float* bs    = (const float*)d_in[4];
    const float* Wh    = (const float*)d_in[5];
    const float* bh    = (const float*)d_in[6];
    const float* Wskip = (const float*)d_in[7];
    const float* Wagg  = (const float*)d_in[8];
    const float* bagg  = (const float*)d_in[9];
    const float* gamma = (const float*)d_in[10];
    const float* beta  = (const float*)d_in[11];
    float* out = (float*)d_out;

    const size_t N = NTOT;
    float* ws   = (float*)d_ws;
    float* agg  = ws;                        // N*256 f32
    float* sbuf = agg  + N*256;              // N*4
    float* hbuf = sbuf + N*4;                // N*64
    int*   idxb = (int*)(hbuf + N*64);       // N*16 int32
    float* ewb  = (float*)(idxb + N*16);     // N*16
    float* sums = ewb + N*16;                // 256  (sum | sumsq)

    hipMemsetAsync(sums, 0, 256*sizeof(float), stream);
    k1_proj<<<NTOT/256, 256, 0, stream>>>(x, Ws, bs, Wh, bh, sbuf, hbuf);
    k2_knn <<<NGRAPH*16, 256, 0, stream>>>(sbuf, idxb, ewb);
    k3_agg <<<NTOT/4,   256, 0, stream>>>(hbuf, z, idxb, ewb, agg);
    k4_gemm<<<NTOT/64,  256, 0, stream>>>(x, agg, Wskip, Wagg, bagg, out, sums);
    k6_bn  <<<NTOT*OUT_CH/4/256, 256, 0, stream>>>(out, sums, gamma, beta);
}

// Round 4
// 321.768 us; speedup vs baseline: 2.3380x; 1.0371x over previous
//
#include <hip/hip_runtime.h>
#include <hip/hip_bf16.h>
#include <math.h>

#define NPG   1024
#define KNN   16
#define IN_CH 64
#define OUT_CH 128
#define SPACE 4
#define PROP  64
#define NGRAPH 64
#define NTOT  (NGRAPH*NPG)   // 65536

typedef unsigned long long u64;
typedef unsigned int u32;

#define K_INF ((0xFF800000ULL << 32) | 0x3FFULL)

// ---------------------------------------------------------------------------
// Kernel 1: s = x@Ws.T + bs ; h = x@Wh.T + bh   (thread per node)
// ---------------------------------------------------------------------------
__global__ __launch_bounds__(256) void k1_proj(
    const float* __restrict__ x, const float* __restrict__ Ws, const float* __restrict__ bs,
    const float* __restrict__ Wh, const float* __restrict__ bh,
    float* __restrict__ s_out, float* __restrict__ h_out)
{
    __shared__ float whl[PROP*IN_CH];   // [p][c]
    __shared__ float wsl[SPACE*IN_CH];  // [d][c]
    int tid = threadIdx.x;
    {
        const float4* src = (const float4*)Wh;
        float4* dst = (float4*)whl;
        for (int e = tid; e < PROP*IN_CH/4; e += 256) dst[e] = src[e];
        if (tid < SPACE*IN_CH/4) ((float4*)wsl)[tid] = ((const float4*)Ws)[tid];
    }
    __syncthreads();
    int i = blockIdx.x*256 + tid;

    float4 xr[16];
    const float4* xrow = (const float4*)(x + (size_t)i*IN_CH);
    #pragma unroll
    for (int q = 0; q < 16; q++) xr[q] = xrow[q];

    #pragma unroll
    for (int d = 0; d < SPACE; d++) {
        float acc = bs[d];
        const float4* wr = (const float4*)(wsl + d*IN_CH);
        #pragma unroll
        for (int q = 0; q < 16; q++) {
            float4 w = wr[q];
            acc += xr[q].x*w.x + xr[q].y*w.y + xr[q].z*w.z + xr[q].w*w.w;
        }
        s_out[(size_t)i*SPACE + d] = acc;
    }
    #pragma unroll 4
    for (int p = 0; p < PROP; p++) {
        float acc = bh[p];
        const float4* wr = (const float4*)(whl + p*IN_CH);
        #pragma unroll
        for (int q = 0; q < 16; q++) {
            float4 w = wr[q];
            acc += xr[q].x*w.x + xr[q].y*w.y + xr[q].z*w.z + xr[q].w*w.w;
        }
        h_out[(size_t)i*PROP + p] = acc;
    }
}

// ---------------------------------------------------------------------------
// Compare-exchange on named u64 registers (NO arrays -> no scratch)
// ---------------------------------------------------------------------------
#define CEU(a,b) { u64 _lo=(a)<(b)?(a):(b); u64 _hi=(a)<(b)?(b):(a); (a)=_lo; (b)=_hi; }
#define CED(a,b) { u64 _lo=(a)<(b)?(a):(b); u64 _hi=(a)<(b)?(b):(a); (a)=_hi; (b)=_lo; }

#define M16N(n0,n1,n2,n3,n4,n5,n6,n7,n8,n9,n10,n11,n12,n13,n14,n15) \
 CEU(n0,n8) CEU(n1,n9) CEU(n2,n10) CEU(n3,n11) CEU(n4,n12) CEU(n5,n13) CEU(n6,n14) CEU(n7,n15) \
 CEU(n0,n4) CEU(n1,n5) CEU(n2,n6) CEU(n3,n7) CEU(n8,n12) CEU(n9,n13) CEU(n10,n14) CEU(n11,n15) \
 CEU(n0,n2) CEU(n1,n3) CEU(n4,n6) CEU(n5,n7) CEU(n8,n10) CEU(n9,n11) CEU(n12,n14) CEU(n13,n15) \
 CEU(n0,n1) CEU(n2,n3) CEU(n4,n5) CEU(n6,n7) CEU(n8,n9) CEU(n10,n11) CEU(n12,n13) CEU(n14,n15)

#define S16N(n0,n1,n2,n3,n4,n5,n6,n7,n8,n9,n10,n11,n12,n13,n14,n15) \
 CEU(n0,n1) CED(n2,n3) CEU(n4,n5) CED(n6,n7) CEU(n8,n9) CED(n10,n11) CEU(n12,n13) CED(n14,n15) \
 CEU(n0,n2) CEU(n1,n3) CED(n4,n6) CED(n5,n7) CEU(n8,n10) CEU(n9,n11) CED(n12,n14) CED(n13,n15) \
 CEU(n0,n1) CEU(n2,n3) CED(n4,n5) CED(n6,n7) CEU(n8,n9) CEU(n10,n11) CED(n12,n13) CED(n14,n15) \
 CEU(n0,n4) CEU(n1,n5) CEU(n2,n6) CEU(n3,n7) CED(n8,n12) CED(n9,n13) CED(n10,n14) CED(n11,n15) \
 CEU(n0,n2) CEU(n1,n3) CEU(n4,n6) CEU(n5,n7) CED(n8,n10) CED(n9,n11) CED(n12,n14) CED(n13,n15) \
 CEU(n0,n1) CEU(n2,n3) CED(n4,n5) CED(n6,n7) CEU(n8,n9) CEU(n10,n11) CED(n12,n13) CED(n14,n15) \
 M16N(n0,n1,n2,n3,n4,n5,n6,n7,n8,n9,n10,n11,n12,n13,n14,n15)

__device__ __forceinline__ float unmono(u32 uw) {
    return __uint_as_float((uw & 0x80000000u) ? (uw & 0x7FFFFFFFu) : ~uw);
}

// pop one 10-bit index from the register queue, build 64-bit key
#define POPN(b, dst) { \
    int _jb = (int)(q0 & 1023u); \
    q0 = (q0 >> 10) | (q1 << 54); q1 = (q1 >> 10) | (q2 << 54); q2 >>= 10; \
    float4 _sb = s4[_jb]; \
    float _dx = si.x-_sb.x, _dy = si.y-_sb.y, _dz = si.z-_sb.z, _dw = si.w-_sb.w; \
    float _db = _dx*_dx + _dy*_dy + _dz*_dz + _dw*_dw; \
    u32 _u = __float_as_uint(_db); _u = (_u >> 31) ? ~_u : (_u | 0x80000000u); \
    dst = ((b) < cnt) ? ((((u64)_u) << 32) | (u32)_jb) : ~0ULL; \
}

#define FLUSHK() do{ \
    u64 n0,n1,n2,n3,n4,n5,n6,n7,n8,n9,n10,n11,n12,n13,n14,n15; \
    POPN(0,n0) POPN(1,n1) POPN(2,n2) POPN(3,n3) POPN(4,n4) POPN(5,n5) POPN(6,n6) POPN(7,n7) \
    POPN(8,n8) POPN(9,n9) POPN(10,n10) POPN(11,n11) POPN(12,n12) POPN(13,n13) POPN(14,n14) POPN(15,n15) \
    S16N(n0,n1,n2,n3,n4,n5,n6,n7,n8,n9,n10,n11,n12,n13,n14,n15) \
    kk0 =kk0 <n15?kk0 :n15; kk1 =kk1 <n14?kk1 :n14; kk2 =kk2 <n13?kk2 :n13; kk3 =kk3 <n12?kk3 :n12; \
    kk4 =kk4 <n11?kk4 :n11; kk5 =kk5 <n10?kk5 :n10; kk6 =kk6 <n9 ?kk6 :n9 ; kk7 =kk7 <n8 ?kk7 :n8 ; \
    kk8 =kk8 <n7 ?kk8 :n7 ; kk9 =kk9 <n6 ?kk9 :n6 ; kk10=kk10<n5 ?kk10:n5 ; kk11=kk11<n4 ?kk11:n4 ; \
    kk12=kk12<n3 ?kk12:n3 ; kk13=kk13<n2 ?kk13:n2 ; kk14=kk14<n1 ?kk14:n1 ; kk15=kk15<n0 ?kk15:n0 ; \
    M16N(kk0,kk1,kk2,kk3,kk4,kk5,kk6,kk7,kk8,kk9,kk10,kk11,kk12,kk13,kk14,kk15) \
    cnt = 0; \
    wf = unmono((u32)(kk15 >> 32)); \
}while(0)

#define SHF64(v,mm) ((u64)__shfl_xor((long long)(v), (mm)))
#define MRG(mm) do{ \
    u64 p0=SHF64(kk15,mm), p1=SHF64(kk14,mm), p2 =SHF64(kk13,mm), p3 =SHF64(kk12,mm); \
    u64 p4=SHF64(kk11,mm), p5=SHF64(kk10,mm), p6 =SHF64(kk9,mm),  p7 =SHF64(kk8,mm); \
    u64 p8=SHF64(kk7,mm),  p9=SHF64(kk6,mm),  p10=SHF64(kk5,mm),  p11=SHF64(kk4,mm); \
    u64 p12=SHF64(kk3,mm), p13=SHF64(kk2,mm), p14=SHF64(kk1,mm),  p15=SHF64(kk0,mm); \
    kk0 =kk0 <p0 ?kk0 :p0 ; kk1 =kk1 <p1 ?kk1 :p1 ; kk2 =kk2 <p2 ?kk2 :p2 ; kk3 =kk3 <p3 ?kk3 :p3 ; \
    kk4 =kk4 <p4 ?kk4 :p4 ; kk5 =kk5 <p5 ?kk5 :p5 ; kk6 =kk6 <p6 ?kk6 :p6 ; kk7 =kk7 <p7 ?kk7 :p7 ; \
    kk8 =kk8 <p8 ?kk8 :p8 ; kk9 =kk9 <p9 ?kk9 :p9 ; kk10=kk10<p10?kk10:p10; kk11=kk11<p11?kk11:p11; \
    kk12=kk12<p12?kk12:p12; kk13=kk13<p13?kk13:p13; kk14=kk14<p14?kk14:p14; kk15=kk15<p15?kk15:p15; \
    M16N(kk0,kk1,kk2,kk3,kk4,kk5,kk6,kk7,kk8,kk9,kk10,kk11,kk12,kk13,kk14,kk15) \
}while(0)

#define OUTE(e, kv) if (((e) & 3) == r) { \
    int _j = (int)((kv) & 1023u); \
    float _d2 = unmono((u32)((kv) >> 32)); \
    ew_out[bq + (e)] = expf(-10.0f * _d2); \
    idx_out[bq + (e)] = gbase + _j; }

// ---------------------------------------------------------------------------
// Kernel 2 v4: exact kNN (K=16). All selection state in NAMED registers.
// lane = 4*query_grp + quarter; thread scans 256 candidates.
// key = (monotonic_u32(d2)<<32) | j  -> exact (d2, j) lexicographic order.
// ---------------------------------------------------------------------------
__global__ __launch_bounds__(256) void k2_knn(
    const float* __restrict__ s, int* __restrict__ idx_out, float* __restrict__ ew_out)
{
    __shared__ float4 s4[NPG];
    int tid = threadIdx.x;
    int g    = blockIdx.x >> 4;
    int gbase = g * NPG;
    int qblk = (blockIdx.x & 15) * 64;
    const float4* sg = (const float4*)(s + (size_t)g*NPG*SPACE);
    for (int e = tid; e < NPG; e += 256) s4[e] = sg[e];
    __syncthreads();

    int lane = tid & 63;
    int grp  = lane >> 2;
    int r    = lane & 3;
    int q    = qblk + (tid >> 6)*16 + grp;
    float4 si = s4[q];

    u64 kk0=K_INF,kk1=K_INF,kk2=K_INF,kk3=K_INF,kk4=K_INF,kk5=K_INF,kk6=K_INF,kk7=K_INF,
        kk8=K_INF,kk9=K_INF,kk10=K_INF,kk11=K_INF,kk12=K_INF,kk13=K_INF,kk14=K_INF,kk15=K_INF;
    float wf = INFINITY;
    int cnt = 0;
    u64 q0 = 0, q1 = 0, q2 = 0;

    #pragma unroll 1
    for (int it = 0; it < 256; ++it) {
        int j = r*256 + ((it + 61*r) & 255);
        float4 sj = s4[j];
        float dx = si.x-sj.x, dy = si.y-sj.y, dz = si.z-sj.z, dw = si.w-sj.w;
        float d2 = dx*dx + dy*dy + dz*dz + dw*dw;
        if ((d2 <= wf) && (j != q)) {
            q2 = (q2 << 10) | (q1 >> 54);
            q1 = (q1 << 10) | (q0 >> 54);
            q0 = (q0 << 10) | (u32)j;
            cnt++;
        }
        if (__any(cnt >= 16)) FLUSHK();
    }
    if (__any(cnt > 0)) FLUSHK();

    MRG(1);
    MRG(2);

    size_t bq = ((size_t)(gbase + q)) * KNN;
    OUTE(0,kk0)  OUTE(1,kk1)  OUTE(2,kk2)  OUTE(3,kk3)
    OUTE(4,kk4)  OUTE(5,kk5)  OUTE(6,kk6)  OUTE(7,kk7)
    OUTE(8,kk8)  OUTE(9,kk9)  OUTE(10,kk10) OUTE(11,kk11)
    OUTE(12,kk12) OUTE(13,kk13) OUTE(14,kk14) OUTE(15,kk15)
}

// ---------------------------------------------------------------------------
// Kernel 34: fused aggregation + GEMM + BN partial stats.
// Phase 0: per-block 64-row agg tile -> bf16 LDS (swizzled), wave-per-node.
// Phase 1: out = x@Wskip.T + agg@Wagg.T + bagg via mfma_f32_16x16x32_bf16;
//          A chunks 1-4 read straight from the agg LDS tile.
// Epilogue: per-channel sum/sumsq -> partial[block][256] (no global atomics).
// ---------------------------------------------------------------------------
typedef __attribute__((ext_vector_type(8))) short bf16x8;
typedef __attribute__((ext_vector_type(4))) float f32x4;

__device__ __forceinline__ u32 pk2bf(float a, float b) {
    u32 ua = __float_as_uint(a);
    u32 ub = __float_as_uint(b);
    ua = (ua + 0x7fffu + ((ua >> 16) & 1u)) >> 16;
    ub = (ub + 0x7fffu + ((ub >> 16) & 1u)) >> 16;
    return (ua & 0xffffu) | (ub << 16);
}
__device__ __forceinline__ unsigned short bfr(float a) {
    u32 ua = __float_as_uint(a);
    ua = (ua + 0x7fffu + ((ua >> 16) & 1u)) >> 16;
    return (unsigned short)ua;
}

__global__ __launch_bounds__(256) void k34_agg_gemm(
    const float* __restrict__ x, const float* __restrict__ h,
    const float* __restrict__ z, const int* __restrict__ idx,
    const float* __restrict__ ew,
    const float* __restrict__ Wskip, const float* __restrict__ Wagg,
    const float* __restrict__ bagg, float* __restrict__ out,
    float* __restrict__ partial)
{
    __shared__ char AggL[64*512];   // [row][256 ch] bf16, swizzled, 32 KB
    __shared__ char Al[64*128];     // x chunk tile
    __shared__ char Bl[128*128];    // weight chunk tile
    __shared__ float st[128], st2[128];
    int tid = threadIdx.x;
    int lane = tid & 63, wid = tid >> 6;
    int bid = blockIdx.x;
    int tile = (bid & 7) * 128 + (bid >> 3);   // XCD-chunked swizzle (1024%8==0)
    int mbase = tile * 64;

    if (tid < 128) { st[tid] = 0.f; st2[tid] = 0.f; }

    // ---- phase 0: aggregation (16 nodes per wave) ----
    #pragma unroll 1
    for (int t = 0; t < 16; ++t) {
        int row = wid*16 + t;
        int node = mbase + row;
        int kq = lane & 15;
        int jv = idx[(size_t)node*KNN + kq];
        float ev = ew[(size_t)node*KNN + kq];
        float dz = z[jv] - z[node];
        float as = fabsf(dz);
        as += __shfl_xor(as, 1); as += __shfl_xor(as, 2);
        as += __shfl_xor(as, 4); as += __shfl_xor(as, 8);
        float F = dz / (as + 1e-8f);
        float mean = 0.f, mx = -INFINITY, sm = 0.f, dv = 0.f;
        #pragma unroll
        for (int k = 0; k < KNN; ++k) {
            int   j = __shfl(jv, k);
            float e = __shfl(ev, k);
            float f = __shfl(F,  k);
            float hv = h[(size_t)j*PROP + lane];
            float m = hv * e;
            mean += m; mx = fmaxf(mx, m);
            sm += m * fabsf(f); dv += m * f;
        }
        int swz = (row & 7) << 4;
        char* rp = AggL + row*512;
        *(unsigned short*)(rp + ((2*(lane      )) ^ swz)) = bfr(mean * 0.0625f);
        *(unsigned short*)(rp + ((2*(lane +  64)) ^ swz)) = bfr(mx);
        *(unsigned short*)(rp + ((2*(lane + 128)) ^ swz)) = bfr(sm * 0.0625f);
        *(unsigned short*)(rp + ((2*(lane + 192)) ^ swz)) = bfr(dv);
    }

    // ---- phase 1: GEMM ----
    int wy = wid >> 1, wx = wid & 1;
    int colb = wx*64 + (lane & 15);
    f32x4 acc[2][4];
    #pragma unroll
    for (int nc = 0; nc < 4; ++nc) {
        float bv = bagg[colb + nc*16];
        #pragma unroll
        for (int mr = 0; mr < 2; ++mr) acc[mr][nc] = (f32x4){bv, bv, bv, bv};
    }

    int arow = tid >> 2, akq = (tid & 3) * 16;
    int brow = tid >> 1, bkq = (tid & 1) * 32;
    int asw = (arow & 7) << 4, bsw = (brow & 7) << 4;

    for (int ch = 0; ch < 5; ++ch) {
        __syncthreads();   // phase-0 done / prev chunk's Bl reads done
        if (ch == 0) {
            const float* ap = x + (size_t)(mbase + arow)*64 + akq;
            float4 f0 = ((const float4*)ap)[0], f1 = ((const float4*)ap)[1];
            float4 f2 = ((const float4*)ap)[2], f3 = ((const float4*)ap)[3];
            uint4 u0 = { pk2bf(f0.x,f0.y), pk2bf(f0.z,f0.w), pk2bf(f1.x,f1.y), pk2bf(f1.z,f1.w) };
            uint4 u1 = { pk2bf(f2.x,f2.y), pk2bf(f2.z,f2.w), pk2bf(f3.x,f3.y), pk2bf(f3.z,f3.w) };
            *(uint4*)(Al + arow*128 + ((akq*2     ) ^ asw)) = u0;
            *(uint4*)(Al + arow*128 + ((akq*2 + 16) ^ asw)) = u1;
        }
        const float* bp = (ch == 0) ? (Wskip + (size_t)brow*64  + bkq)
                                    : (Wagg  + (size_t)brow*256 + (ch-1)*64 + bkq);
        #pragma unroll
        for (int g2 = 0; g2 < 4; ++g2) {
            float4 f0 = ((const float4*)bp)[2*g2], f1 = ((const float4*)bp)[2*g2+1];
            uint4 u = { pk2bf(f0.x,f0.y), pk2bf(f0.z,f0.w), pk2bf(f1.x,f1.y), pk2bf(f1.z,f1.w) };
            *(uint4*)(Bl + brow*128 + ((bkq*2 + g2*16) ^ bsw)) = u;
        }
        __syncthreads();

        const char* ab; int astr; int kofs;
        if (ch == 0) { ab = Al;   astr = 128; kofs = 0; }
        else         { ab = AggL; astr = 512; kofs = (ch-1)*128; }

        #pragma unroll
        for (int ks = 0; ks < 2; ++ks) {
            int kb = ks*64 + ((lane >> 4) * 16);
            bf16x8 af[2], bfrg[4];
            #pragma unroll
            for (int mr = 0; mr < 2; ++mr) {
                int row = wy*32 + mr*16 + (lane & 15);
                af[mr] = *(const bf16x8*)(ab + row*astr + kofs + (kb ^ ((row & 7) << 4)));
            }
            #pragma unroll
            for (int nc = 0; nc < 4; ++nc) {
                int n = wx*64 + nc*16 + (lane & 15);
                bfrg[nc] = *(const bf16x8*)(Bl + n*128 + (kb ^ ((n & 7) << 4)));
            }
            #pragma unroll
            for (int mr = 0; mr < 2; ++mr)
                #pragma unroll
                for (int nc = 0; nc < 4; ++nc)
                    acc[mr][nc] = __builtin_amdgcn_mfma_f32_16x16x32_bf16(
                        af[mr], bfrg[nc], acc[mr][nc], 0, 0, 0);
        }
    }

    // ---- epilogue: store + per-channel BN partial stats ----
    float s1[4] = {0,0,0,0}, s2[4] = {0,0,0,0};
    #pragma unroll
    for (int mr = 0; mr < 2; ++mr) {
        int r0 = mbase + wy*32 + mr*16 + (lane >> 4)*4;
        #pragma unroll
        for (int nc = 0; nc < 4; ++nc) {
            int c = colb + nc*16;
            #pragma unroll
            for (int j = 0; j < 4; ++j) {
                float v = acc[mr][nc][j];
                out[(size_t)(r0 + j)*OUT_CH + c] = v;
                s1[nc] += v;
                s2[nc] += v*v;
            }
        }
    }
    #pragma unroll
    for (int nc = 0; nc < 4; ++nc) {
        s1[nc] += __shfl_xor(s1[nc], 16); s1[nc] += __shfl_xor(s1[nc], 32);
        s2[nc] += __shfl_xor(s2[nc], 16); s2[nc] += __shfl_xor(s2[nc], 32);
    }
    __syncthreads();
    if ((lane >> 4) == 0) {
        #pragma unroll
        for (int nc = 0; nc < 4; ++nc) {
            atomicAdd(&st[colb + nc*16],  s1[nc]);
            atomicAdd(&st2[colb + nc*16], s2[nc]);
        }
    }
    __syncthreads();
    if (tid < 128) {
        partial[(size_t)bid*256 + tid]       = st[tid];
        partial[(size_t)bid*256 + 128 + tid] = st2[tid];
    }
}

// ---------------------------------------------------------------------------
// Kernel 5r: reduce 1024 block-partials -> sums[256]
// ---------------------------------------------------------------------------
__global__ __launch_bounds__(256) void k5_red(
    const float* __restrict__ partial, float* __restrict__ sums)
{
    int c = threadIdx.x;
    int b0 = blockIdx.x * 32;
    float acc = 0.f;
    #pragma unroll 8
    for (int b = 0; b < 32; ++b)
        acc += partial[(size_t)(b0 + b)*256 + c];
    atomicAdd(&sums[c], acc);
}

// ---------------------------------------------------------------------------
// Kernel 6: BatchNorm (training stats, biased var) + ReLU, in place on d_out
// ---------------------------------------------------------------------------
__global__ __launch_bounds__(256) void k6_bn(
    float* __restrict__ out, const float* __restrict__ sums,
    const float* __restrict__ gamma, const float* __restrict__ beta)
{
    int f = blockIdx.x*256 + threadIdx.x;     // float4 index
    float4 v = *(float4*)(out + (size_t)f*4);
    int o0 = (f*4) & 127;
    const float invN = 1.f / (float)NTOT;
    float r[4] = {v.x, v.y, v.z, v.w};
    #pragma unroll
    for (int c = 0; c < 4; c++) {
        int o = o0 + c;
        float mu  = sums[o] * invN;
        float var = sums[128+o] * invN - mu*mu;
        float sc  = gamma[o] * rsqrtf(var + 1e-5f);
        float sh  = beta[o] - mu*sc;
        float y = r[c]*sc + sh;
        r[c] = y > 0.f ? y : 0.f;
    }
    *(float4*)(out + (size_t)f*4) = make_float4(r[0], r[1], r[2], r[3]);
}

// ---------------------------------------------------------------------------
extern "C" void kernel_launch(void* const* d_in, const int* in_sizes, int n_in,
                              void* d_out, int out_size, void* d_ws, size_t ws_size,
                              hipStream_t stream)
{
    (void)in_sizes; (void)n_in; (void)out_size; (void)ws_size;
    const float* x     = (const float*)d_in[0];
    const float* z     = (const float*)d_in[1];
    /* d_in[2] = batch (int32) — graphs are fixed contiguous blocks, unused */
    const float* Ws    = (const float*)d_in[3];
    const float* bs    = (const float*)d_in[4];
    const float* Wh    = (const float*)d_in[5];
    const float* bh    = (const float*)d_in[6];
    const float* Wskip = (const float*)d_in[7];
    const float* Wagg  = (const float*)d_in[8];
    const float* bagg  = (const float*)d_in[9];
    const float* gamma = (const float*)d_in[10];
    const float* beta  = (const float*)d_in[11];
    float* out = (float*)d_out;

    const size_t N = NTOT;
    float* ws   = (float*)d_ws;
    float* sbuf = ws;                        // N*4
    float* hbuf = sbuf + N*4;                // N*64
    int*   idxb = (int*)(hbuf + N*64);       // N*16 int32
    float* ewb  = (float*)(idxb + N*16);     // N*16
    float* part = ewb + N*16;                // 1024*256
    float* sums = part + 1024*256;           // 256

    hipMemsetAsync(sums, 0, 256*sizeof(float), stream);
    k1_proj<<<NTOT/256, 256, 0, stream>>>(x, Ws, bs, Wh, bh, sbuf, hbuf);
    k2_knn <<<NGRAPH*16, 256, 0, stream>>>(sbuf, idxb, ewb);
    k34_agg_gemm<<<NTOT/64, 256, 0, stream>>>(x, hbuf, z, idxb, ewb,
                                              Wskip, Wagg, bagg, out, part);
    k5_red<<<32, 256, 0, stream>>>(part, sums);
    k6_bn <<<NTOT*OUT_CH/4/256, 256, 0, stream>>>(out, sums, gamma, beta);
}

// Round 5
// 315.384 us; speedup vs baseline: 2.3853x; 1.0202x over previous
//
#include <hip/hip_runtime.h>
#include <hip/hip_bf16.h>
#include <math.h>

#define NPG   1024
#define KNN   16
#define IN_CH 64
#define OUT_CH 128
#define SPACE 4
#define PROP  64
#define NGRAPH 64
#define NTOT  (NGRAPH*NPG)   // 65536

typedef unsigned long long u64;
typedef unsigned int u32;

#define K_INF ((0xFF800000ULL << 32) | 0x3FFULL)

// ---------------------------------------------------------------------------
// Kernel 1: s = x@Ws.T + bs ; h = x@Wh.T + bh   (thread per node)
// ---------------------------------------------------------------------------
__global__ __launch_bounds__(256) void k1_proj(
    const float* __restrict__ x, const float* __restrict__ Ws, const float* __restrict__ bs,
    const float* __restrict__ Wh, const float* __restrict__ bh,
    float* __restrict__ s_out, float* __restrict__ h_out)
{
    __shared__ float whl[PROP*IN_CH];   // [p][c]
    __shared__ float wsl[SPACE*IN_CH];  // [d][c]
    int tid = threadIdx.x;
    {
        const float4* src = (const float4*)Wh;
        float4* dst = (float4*)whl;
        for (int e = tid; e < PROP*IN_CH/4; e += 256) dst[e] = src[e];
        if (tid < SPACE*IN_CH/4) ((float4*)wsl)[tid] = ((const float4*)Ws)[tid];
    }
    __syncthreads();
    int i = blockIdx.x*256 + tid;

    float4 xr[16];
    const float4* xrow = (const float4*)(x + (size_t)i*IN_CH);
    #pragma unroll
    for (int q = 0; q < 16; q++) xr[q] = xrow[q];

    #pragma unroll
    for (int d = 0; d < SPACE; d++) {
        float acc = bs[d];
        const float4* wr = (const float4*)(wsl + d*IN_CH);
        #pragma unroll
        for (int q = 0; q < 16; q++) {
            float4 w = wr[q];
            acc += xr[q].x*w.x + xr[q].y*w.y + xr[q].z*w.z + xr[q].w*w.w;
        }
        s_out[(size_t)i*SPACE + d] = acc;
    }
    #pragma unroll 4
    for (int p = 0; p < PROP; p++) {
        float acc = bh[p];
        const float4* wr = (const float4*)(whl + p*IN_CH);
        #pragma unroll
        for (int q = 0; q < 16; q++) {
            float4 w = wr[q];
            acc += xr[q].x*w.x + xr[q].y*w.y + xr[q].z*w.z + xr[q].w*w.w;
        }
        h_out[(size_t)i*PROP + p] = acc;
    }
}

// ---------------------------------------------------------------------------
// Compare-exchange on named u64 registers (NO arrays -> no scratch)
// ---------------------------------------------------------------------------
#define CEU(a,b) { u64 _lo=(a)<(b)?(a):(b); u64 _hi=(a)<(b)?(b):(a); (a)=_lo; (b)=_hi; }
#define CED(a,b) { u64 _lo=(a)<(b)?(a):(b); u64 _hi=(a)<(b)?(b):(a); (a)=_hi; (b)=_lo; }

#define M16N(n0,n1,n2,n3,n4,n5,n6,n7,n8,n9,n10,n11,n12,n13,n14,n15) \
 CEU(n0,n8) CEU(n1,n9) CEU(n2,n10) CEU(n3,n11) CEU(n4,n12) CEU(n5,n13) CEU(n6,n14) CEU(n7,n15) \
 CEU(n0,n4) CEU(n1,n5) CEU(n2,n6) CEU(n3,n7) CEU(n8,n12) CEU(n9,n13) CEU(n10,n14) CEU(n11,n15) \
 CEU(n0,n2) CEU(n1,n3) CEU(n4,n6) CEU(n5,n7) CEU(n8,n10) CEU(n9,n11) CEU(n12,n14) CEU(n13,n15) \
 CEU(n0,n1) CEU(n2,n3) CEU(n4,n5) CEU(n6,n7) CEU(n8,n9) CEU(n10,n11) CEU(n12,n13) CEU(n14,n15)

#define S16N(n0,n1,n2,n3,n4,n5,n6,n7,n8,n9,n10,n11,n12,n13,n14,n15) \
 CEU(n0,n1) CED(n2,n3) CEU(n4,n5) CED(n6,n7) CEU(n8,n9) CED(n10,n11) CEU(n12,n13) CED(n14,n15) \
 CEU(n0,n2) CEU(n1,n3) CED(n4,n6) CED(n5,n7) CEU(n8,n10) CEU(n9,n11) CED(n12,n14) CED(n13,n15) \
 CEU(n0,n1) CEU(n2,n3) CED(n4,n5) CED(n6,n7) CEU(n8,n9) CEU(n10,n11) CED(n12,n13) CED(n14,n15) \
 CEU(n0,n4) CEU(n1,n5) CEU(n2,n6) CEU(n3,n7) CED(n8,n12) CED(n9,n13) CED(n10,n14) CED(n11,n15) \
 CEU(n0,n2) CEU(n1,n3) CEU(n4,n6) CEU(n5,n7) CED(n8,n10) CED(n9,n11) CED(n12,n14) CED(n13,n15) \
 CEU(n0,n1) CEU(n2,n3) CED(n4,n5) CED(n6,n7) CEU(n8,n9) CEU(n10,n11) CED(n12,n13) CED(n14,n15) \
 M16N(n0,n1,n2,n3,n4,n5,n6,n7,n8,n9,n10,n11,n12,n13,n14,n15)

__device__ __forceinline__ float unmono(u32 uw) {
    return __uint_as_float((uw & 0x80000000u) ? (uw & 0x7FFFFFFFu) : ~uw);
}

// pop one 10-bit index from the register queue, build 64-bit key
#define POPN(b, dst) { \
    int _jb = (int)(q0 & 1023u); \
    q0 = (q0 >> 10) | (q1 << 54); q1 = (q1 >> 10) | (q2 << 54); q2 >>= 10; \
    float4 _sb = s4[_jb]; \
    float _dx = si.x-_sb.x, _dy = si.y-_sb.y, _dz = si.z-_sb.z, _dw = si.w-_sb.w; \
    float _db = _dx*_dx + _dy*_dy + _dz*_dz + _dw*_dw; \
    u32 _u = __float_as_uint(_db); _u = (_u >> 31) ? ~_u : (_u | 0x80000000u); \
    dst = ((b) < cnt) ? ((((u64)_u) << 32) | (u32)_jb) : ~0ULL; \
}

#define FLUSHK() do{ \
    u64 n0,n1,n2,n3,n4,n5,n6,n7,n8,n9,n10,n11,n12,n13,n14,n15; \
    POPN(0,n0) POPN(1,n1) POPN(2,n2) POPN(3,n3) POPN(4,n4) POPN(5,n5) POPN(6,n6) POPN(7,n7) \
    POPN(8,n8) POPN(9,n9) POPN(10,n10) POPN(11,n11) POPN(12,n12) POPN(13,n13) POPN(14,n14) POPN(15,n15) \
    S16N(n0,n1,n2,n3,n4,n5,n6,n7,n8,n9,n10,n11,n12,n13,n14,n15) \
    kk0 =kk0 <n15?kk0 :n15; kk1 =kk1 <n14?kk1 :n14; kk2 =kk2 <n13?kk2 :n13; kk3 =kk3 <n12?kk3 :n12; \
    kk4 =kk4 <n11?kk4 :n11; kk5 =kk5 <n10?kk5 :n10; kk6 =kk6 <n9 ?kk6 :n9 ; kk7 =kk7 <n8 ?kk7 :n8 ; \
    kk8 =kk8 <n7 ?kk8 :n7 ; kk9 =kk9 <n6 ?kk9 :n6 ; kk10=kk10<n5 ?kk10:n5 ; kk11=kk11<n4 ?kk11:n4 ; \
    kk12=kk12<n3 ?kk12:n3 ; kk13=kk13<n2 ?kk13:n2 ; kk14=kk14<n1 ?kk14:n1 ; kk15=kk15<n0 ?kk15:n0 ; \
    M16N(kk0,kk1,kk2,kk3,kk4,kk5,kk6,kk7,kk8,kk9,kk10,kk11,kk12,kk13,kk14,kk15) \
    cnt = 0; \
    wf = unmono((u32)(kk15 >> 32)); \
}while(0)

#define SHF64(v,mm) ((u64)__shfl_xor((long long)(v), (mm)))
#define MRG(mm) do{ \
    u64 p0=SHF64(kk15,mm), p1=SHF64(kk14,mm), p2 =SHF64(kk13,mm), p3 =SHF64(kk12,mm); \
    u64 p4=SHF64(kk11,mm), p5=SHF64(kk10,mm), p6 =SHF64(kk9,mm),  p7 =SHF64(kk8,mm); \
    u64 p8=SHF64(kk7,mm),  p9=SHF64(kk6,mm),  p10=SHF64(kk5,mm),  p11=SHF64(kk4,mm); \
    u64 p12=SHF64(kk3,mm), p13=SHF64(kk2,mm), p14=SHF64(kk1,mm),  p15=SHF64(kk0,mm); \
    kk0 =kk0 <p0 ?kk0 :p0 ; kk1 =kk1 <p1 ?kk1 :p1 ; kk2 =kk2 <p2 ?kk2 :p2 ; kk3 =kk3 <p3 ?kk3 :p3 ; \
    kk4 =kk4 <p4 ?kk4 :p4 ; kk5 =kk5 <p5 ?kk5 :p5 ; kk6 =kk6 <p6 ?kk6 :p6 ; kk7 =kk7 <p7 ?kk7 :p7 ; \
    kk8 =kk8 <p8 ?kk8 :p8 ; kk9 =kk9 <p9 ?kk9 :p9 ; kk10=kk10<p10?kk10:p10; kk11=kk11<p11?kk11:p11; \
    kk12=kk12<p12?kk12:p12; kk13=kk13<p13?kk13:p13; kk14=kk14<p14?kk14:p14; kk15=kk15<p15?kk15:p15; \
    M16N(kk0,kk1,kk2,kk3,kk4,kk5,kk6,kk7,kk8,kk9,kk10,kk11,kk12,kk13,kk14,kk15) \
}while(0)

#define OUTE(e, kv) if (((e) & 3) == r) { \
    int _j = (int)((kv) & 1023u); \
    float _d2 = unmono((u32)((kv) >> 32)); \
    ew_out[bq + (e)] = expf(-10.0f * _d2); \
    idx_out[bq + (e)] = gbase + _j; }

// ---------------------------------------------------------------------------
// Kernel 2 v5: exact kNN (K=16). All selection state in NAMED registers,
// amdgpu_waves_per_eu(4,4) pins the occupancy target to 4 waves/EU
// (= measured occupancy) so the register allocator gets a 128-VGPR budget
// and stops spilling kk0..kk15 to scratch around each flush.
// ---------------------------------------------------------------------------
__attribute__((amdgpu_waves_per_eu(4, 4)))
__global__ __launch_bounds__(256) void k2_knn(
    const float* __restrict__ s, int* __restrict__ idx_out, float* __restrict__ ew_out)
{
    __shared__ float4 s4[NPG];
    int tid = threadIdx.x;
    int g    = blockIdx.x >> 4;
    int gbase = g * NPG;
    int qblk = (blockIdx.x & 15) * 64;
    const float4* sg = (const float4*)(s + (size_t)g*NPG*SPACE);
    for (int e = tid; e < NPG; e += 256) s4[e] = sg[e];
    __syncthreads();

    int lane = tid & 63;
    int grp  = lane >> 2;
    int r    = lane & 3;
    int q    = qblk + (tid >> 6)*16 + grp;
    float4 si = s4[q];

    u64 kk0=K_INF,kk1=K_INF,kk2=K_INF,kk3=K_INF,kk4=K_INF,kk5=K_INF,kk6=K_INF,kk7=K_INF,
        kk8=K_INF,kk9=K_INF,kk10=K_INF,kk11=K_INF,kk12=K_INF,kk13=K_INF,kk14=K_INF,kk15=K_INF;
    float wf = INFINITY;
    int cnt = 0;
    u64 q0 = 0, q1 = 0, q2 = 0;

    #pragma unroll 1
    for (int it = 0; it < 256; ++it) {
        int j = r*256 + ((it + 61*r) & 255);
        float4 sj = s4[j];
        float dx = si.x-sj.x, dy = si.y-sj.y, dz = si.z-sj.z, dw = si.w-sj.w;
        float d2 = dx*dx + dy*dy + dz*dz + dw*dw;
        if ((d2 <= wf) && (j != q)) {
            q2 = (q2 << 10) | (q1 >> 54);
            q1 = (q1 << 10) | (q0 >> 54);
            q0 = (q0 << 10) | (u32)j;
            cnt++;
        }
        if (__any(cnt >= 16)) FLUSHK();
    }
    if (__any(cnt > 0)) FLUSHK();

    MRG(1);
    MRG(2);

    size_t bq = ((size_t)(gbase + q)) * KNN;
    OUTE(0,kk0)  OUTE(1,kk1)  OUTE(2,kk2)  OUTE(3,kk3)
    OUTE(4,kk4)  OUTE(5,kk5)  OUTE(6,kk6)  OUTE(7,kk7)
    OUTE(8,kk8)  OUTE(9,kk9)  OUTE(10,kk10) OUTE(11,kk11)
    OUTE(12,kk12) OUTE(13,kk13) OUTE(14,kk14) OUTE(15,kk15)
}

// ---------------------------------------------------------------------------
// Kernel 34 v2: fused aggregation + GEMM + BN partial stats.
// Phase 0: per-block 64-row agg tile -> bf16 LDS (swizzled), wave-per-node,
//          unroll-2 to double in-flight gathers.
// Phase 1: out = x@Wskip.T + agg@Wagg.T + bagg via mfma_f32_16x16x32_bf16.
//          Chunk 0's A-fragments convert straight from global x (no Al tile)
//          -> LDS 49 KB -> 3 blocks/CU.
// Epilogue: per-channel sum/sumsq -> partial[block][256] (no global atomics).
// ---------------------------------------------------------------------------
typedef __attribute__((ext_vector_type(8))) short bf16x8;
typedef __attribute__((ext_vector_type(4))) float f32x4;

__device__ __forceinline__ u32 pk2bf(float a, float b) {
    u32 ua = __float_as_uint(a);
    u32 ub = __float_as_uint(b);
    ua = (ua + 0x7fffu + ((ua >> 16) & 1u)) >> 16;
    ub = (ub + 0x7fffu + ((ub >> 16) & 1u)) >> 16;
    return (ua & 0xffffu) | (ub << 16);
}
__device__ __forceinline__ unsigned short bfr(float a) {
    u32 ua = __float_as_uint(a);
    ua = (ua + 0x7fffu + ((ua >> 16) & 1u)) >> 16;
    return (unsigned short)ua;
}

__global__ __launch_bounds__(256) void k34_agg_gemm(
    const float* __restrict__ x, const float* __restrict__ h,
    const float* __restrict__ z, const int* __restrict__ idx,
    const float* __restrict__ ew,
    const float* __restrict__ Wskip, const float* __restrict__ Wagg,
    const float* __restrict__ bagg, float* __restrict__ out,
    float* __restrict__ partial)
{
    __shared__ char AggL[64*512];   // [row][256 ch] bf16, swizzled, 32 KB
    __shared__ char Bl[128*128];    // weight chunk tile, 16 KB
    __shared__ float st[128], st2[128];
    int tid = threadIdx.x;
    int lane = tid & 63, wid = tid >> 6;
    int bid = blockIdx.x;
    int tile = (bid & 7) * 128 + (bid >> 3);   // XCD-chunked swizzle (1024%8==0)
    int mbase = tile * 64;

    if (tid < 128) { st[tid] = 0.f; st2[tid] = 0.f; }

    // ---- phase 0: aggregation (16 nodes per wave) ----
    #pragma unroll 2
    for (int t = 0; t < 16; ++t) {
        int row = wid*16 + t;
        int node = mbase + row;
        int kq = lane & 15;
        int jv = idx[(size_t)node*KNN + kq];
        float ev = ew[(size_t)node*KNN + kq];
        float dz = z[jv] - z[node];
        float as = fabsf(dz);
        as += __shfl_xor(as, 1); as += __shfl_xor(as, 2);
        as += __shfl_xor(as, 4); as += __shfl_xor(as, 8);
        float F = dz / (as + 1e-8f);
        float mean = 0.f, mx = -INFINITY, sm = 0.f, dv = 0.f;
        #pragma unroll
        for (int k = 0; k < KNN; ++k) {
            int   j = __shfl(jv, k);
            float e = __shfl(ev, k);
            float f = __shfl(F,  k);
            float hv = h[(size_t)j*PROP + lane];
            float m = hv * e;
            mean += m; mx = fmaxf(mx, m);
            sm += m * fabsf(f); dv += m * f;
        }
        int swz = (row & 7) << 4;
        char* rp = AggL + row*512;
        *(unsigned short*)(rp + ((2*(lane      )) ^ swz)) = bfr(mean * 0.0625f);
        *(unsigned short*)(rp + ((2*(lane +  64)) ^ swz)) = bfr(mx);
        *(unsigned short*)(rp + ((2*(lane + 128)) ^ swz)) = bfr(sm * 0.0625f);
        *(unsigned short*)(rp + ((2*(lane + 192)) ^ swz)) = bfr(dv);
    }

    // ---- phase 1: GEMM ----
    int wy = wid >> 1, wx = wid & 1;
    int colb = wx*64 + (lane & 15);
    f32x4 acc[2][4];
    #pragma unroll
    for (int nc = 0; nc < 4; ++nc) {
        float bv = bagg[colb + nc*16];
        #pragma unroll
        for (int mr = 0; mr < 2; ++mr) acc[mr][nc] = (f32x4){bv, bv, bv, bv};
    }

    int brow = tid >> 1, bkq = (tid & 1) * 32;
    int bsw = (brow & 7) << 4;

    for (int ch = 0; ch < 5; ++ch) {
        __syncthreads();   // phase-0 done / prev chunk's Bl reads done
        const float* bp = (ch == 0) ? (Wskip + (size_t)brow*64  + bkq)
                                    : (Wagg  + (size_t)brow*256 + (ch-1)*64 + bkq);
        #pragma unroll
        for (int g2 = 0; g2 < 4; ++g2) {
            float4 f0 = ((const float4*)bp)[2*g2], f1 = ((const float4*)bp)[2*g2+1];
            uint4 u = { pk2bf(f0.x,f0.y), pk2bf(f0.z,f0.w), pk2bf(f1.x,f1.y), pk2bf(f1.z,f1.w) };
            *(uint4*)(Bl + brow*128 + ((bkq*2 + g2*16) ^ bsw)) = u;
        }
        __syncthreads();

        #pragma unroll
        for (int ks = 0; ks < 2; ++ks) {
            int kb = ks*64 + ((lane >> 4) * 16);     // byte offset in 128B row
            bf16x8 af[2], bfrg[4];
            if (ch == 0) {
                // A-fragments straight from global x (f32 -> bf16)
                int ke = ks*32 + (lane >> 4)*8;      // element offset
                #pragma unroll
                for (int mr = 0; mr < 2; ++mr) {
                    int row = mbase + wy*32 + mr*16 + (lane & 15);
                    const float* xp = x + (size_t)row*64 + ke;
                    float4 f0 = *(const float4*)xp, f1 = *(const float4*)(xp + 4);
                    union { u32 u[4]; bf16x8 v; } cv;
                    cv.u[0] = pk2bf(f0.x,f0.y); cv.u[1] = pk2bf(f0.z,f0.w);
                    cv.u[2] = pk2bf(f1.x,f1.y); cv.u[3] = pk2bf(f1.z,f1.w);
                    af[mr] = cv.v;
                }
            } else {
                #pragma unroll
                for (int mr = 0; mr < 2; ++mr) {
                    int row = wy*32 + mr*16 + (lane & 15);
                    af[mr] = *(const bf16x8*)(AggL + row*512 + (ch-1)*128
                                              + (kb ^ ((row & 7) << 4)));
                }
            }
            #pragma unroll
            for (int nc = 0; nc < 4; ++nc) {
                int n = wx*64 + nc*16 + (lane & 15);
                bfrg[nc] = *(const bf16x8*)(Bl + n*128 + (kb ^ ((n & 7) << 4)));
            }
            #pragma unroll
            for (int mr = 0; mr < 2; ++mr)
                #pragma unroll
                for (int nc = 0; nc < 4; ++nc)
                    acc[mr][nc] = __builtin_amdgcn_mfma_f32_16x16x32_bf16(
                        af[mr], bfrg[nc], acc[mr][nc], 0, 0, 0);
        }
    }

    // ---- epilogue: store + per-channel BN partial stats ----
    float s1[4] = {0,0,0,0}, s2[4] = {0,0,0,0};
    #pragma unroll
    for (int mr = 0; mr < 2; ++mr) {
        int r0 = mbase + wy*32 + mr*16 + (lane >> 4)*4;
        #pragma unroll
        for (int nc = 0; nc < 4; ++nc) {
            int c = colb + nc*16;
            #pragma unroll
            for (int j = 0; j < 4; ++j) {
                float v = acc[mr][nc][j];
                out[(size_t)(r0 + j)*OUT_CH + c] = v;
                s1[nc] += v;
                s2[nc] += v*v;
            }
        }
    }
    #pragma unroll
    for (int nc = 0; nc < 4; ++nc) {
        s1[nc] += __shfl_xor(s1[nc], 16); s1[nc] += __shfl_xor(s1[nc], 32);
        s2[nc] += __shfl_xor(s2[nc], 16); s2[nc] += __shfl_xor(s2[nc], 32);
    }
    __syncthreads();
    if ((lane >> 4) == 0) {
        #pragma unroll
        for (int nc = 0; nc < 4; ++nc) {
            atomicAdd(&st[colb + nc*16],  s1[nc]);
            atomicAdd(&st2[colb + nc*16], s2[nc]);
        }
    }
    __syncthreads();
    if (tid < 128) {
        partial[(size_t)bid*256 + tid]       = st[tid];
        partial[(size_t)bid*256 + 128 + tid] = st2[tid];
    }
}

// ---------------------------------------------------------------------------
// Kernel 5r: reduce 1024 block-partials -> sums[256]
// ---------------------------------------------------------------------------
__global__ __launch_bounds__(256) void k5_red(
    const float* __restrict__ partial, float* __restrict__ sums)
{
    int c = threadIdx.x;
    int b0 = blockIdx.x * 32;
    float acc = 0.f;
    #pragma unroll 8
    for (int b = 0; b < 32; ++b)
        acc += partial[(size_t)(b0 + b)*256 + c];
    atomicAdd(&sums[c], acc);
}

// ---------------------------------------------------------------------------
// Kernel 6: BatchNorm (training stats, biased var) + ReLU, in place on d_out
// ---------------------------------------------------------------------------
__global__ __launch_bounds__(256) void k6_bn(
    float* __restrict__ out, const float* __restrict__ sums,
    const float* __restrict__ gamma, const float* __restrict__ beta)
{
    int f = blockIdx.x*256 + threadIdx.x;     // float4 index
    float4 v = *(float4*)(out + (size_t)f*4);
    int o0 = (f*4) & 127;
    const float invN = 1.f / (float)NTOT;
    float r[4] = {v.x, v.y, v.z, v.w};
    #pragma unroll
    for (int c = 0; c < 4; c++) {
        int o = o0 + c;
        float mu  = sums[o] * invN;
        float var = sums[128+o] * invN - mu*mu;
        float sc  = gamma[o] * rsqrtf(var + 1e-5f);
        float sh  = beta[o] - mu*sc;
        float y = r[c]*sc + sh;
        r[c] = y > 0.f ? y : 0.f;
    }
    *(float4*)(out + (size_t)f*4) = make_float4(r[0], r[1], r[2], r[3]);
}

// ---------------------------------------------------------------------------
extern "C" void kernel_launch(void* const* d_in, const int* in_sizes, int n_in,
                              void* d_out, int out_size, void* d_ws, size_t ws_size,
                              hipStream_t stream)
{
    (void)in_sizes; (void)n_in; (void)out_size; (void)ws_size;
    const float* x     = (const float*)d_in[0];
    const float* z     = (const float*)d_in[1];
    /* d_in[2] = batch (int32) — graphs are fixed contiguous blocks, unused */
    const float* Ws    = (const float*)d_in[3];
    const float* bs    = (const float*)d_in[4];
    const float* Wh    = (const float*)d_in[5];
    const float* bh    = (const float*)d_in[6];
    const float* Wskip = (const float*)d_in[7];
    const float* Wagg  = (const float*)d_in[8];
    const float* bagg  = (const float*)d_in[9];
    const float* gamma = (const float*)d_in[10];
    const float* beta  = (const float*)d_in[11];
    float* out = (float*)d_out;

    const size_t N = NTOT;
    float* ws   = (float*)d_ws;
    float* sbuf = ws;                        // N*4
    float* hbuf = sbuf + N*4;                // N*64
    int*   idxb = (int*)(hbuf + N*64);       // N*16 int32
    float* ewb  = (float*)(idxb + N*16);     // N*16
    float* part = ewb + N*16;                // 1024*256
    float* sums = part + 1024*256;           // 256

    hipMemsetAsync(sums, 0, 256*sizeof(float), stream);
    k1_proj<<<NTOT/256, 256, 0, stream>>>(x, Ws, bs, Wh, bh, sbuf, hbuf);
    k2_knn <<<NGRAPH*16, 256, 0, stream>>>(sbuf, idxb, ewb);
    k34_agg_gemm<<<NTOT/64, 256, 0, stream>>>(x, hbuf, z, idxb, ewb,
                                              Wskip, Wagg, bagg, out, part);
    k5_red<<<32, 256, 0, stream>>>(part, sums);
    k6_bn <<<NTOT*OUT_CH/4/256, 256, 0, stream>>>(out, sums, gamma, beta);
}

// Round 8
// 269.037 us; speedup vs baseline: 2.7962x; 1.1723x over previous
//
#include <hip/hip_runtime.h>
#include <hip/hip_bf16.h>
#include <math.h>

#define NPG   1024
#define KNN   16
#define IN_CH 64
#define OUT_CH 128
#define SPACE 4
#define PROP  64
#define NGRAPH 64
#define NTOT  (NGRAPH*NPG)   // 65536

typedef unsigned long long u64;
typedef unsigned int u32;

// ---------------------------------------------------------------------------
// Kernel 1: s = x@Ws.T + bs ; h = x@Wh.T + bh   (thread per node)
// ---------------------------------------------------------------------------
__global__ __launch_bounds__(256) void k1_proj(
    const float* __restrict__ x, const float* __restrict__ Ws, const float* __restrict__ bs,
    const float* __restrict__ Wh, const float* __restrict__ bh,
    float* __restrict__ s_out, float* __restrict__ h_out)
{
    __shared__ float whl[PROP*IN_CH];   // [p][c]
    __shared__ float wsl[SPACE*IN_CH];  // [d][c]
    int tid = threadIdx.x;
    {
        const float4* src = (const float4*)Wh;
        float4* dst = (float4*)whl;
        for (int e = tid; e < PROP*IN_CH/4; e += 256) dst[e] = src[e];
        if (tid < SPACE*IN_CH/4) ((float4*)wsl)[tid] = ((const float4*)Ws)[tid];
    }
    __syncthreads();
    int i = blockIdx.x*256 + tid;

    float4 xr[16];
    const float4* xrow = (const float4*)(x + (size_t)i*IN_CH);
    #pragma unroll
    for (int q = 0; q < 16; q++) xr[q] = xrow[q];

    #pragma unroll
    for (int d = 0; d < SPACE; d++) {
        float acc = bs[d];
        const float4* wr = (const float4*)(wsl + d*IN_CH);
        #pragma unroll
        for (int q = 0; q < 16; q++) {
            float4 w = wr[q];
            acc += xr[q].x*w.x + xr[q].y*w.y + xr[q].z*w.z + xr[q].w*w.w;
        }
        s_out[(size_t)i*SPACE + d] = acc;
    }
    #pragma unroll 4
    for (int p = 0; p < PROP; p++) {
        float acc = bh[p];
        const float4* wr = (const float4*)(whl + p*IN_CH);
        #pragma unroll
        for (int q = 0; q < 16; q++) {
            float4 w = wr[q];
            acc += xr[q].x*w.x + xr[q].y*w.y + xr[q].z*w.z + xr[q].w*w.w;
        }
        h_out[(size_t)i*PROP + p] = acc;
    }
}

// ---------------------------------------------------------------------------
// k2 v6 primitives: u32 keys, branchless med3 sorted-insert, bitonic merge.
// key = (float_bits(d2) & ~1023) | j   -- d2>=0 so bits are u32-monotone;
// low 10 bits = j reproduce lax.top_k's smallest-index tie-break.
// ---------------------------------------------------------------------------
#define MED3(d, x, a, b) asm("v_med3_u32 %0, %1, %2, %3" : "=v"(d) : "v"(x), "v"(a), "v"(b))
#define UMIN(a,b) ((a)<(b)?(a):(b))

// branchless sorted insert (list ascending kk0..kk15, kk15 = worst, dropped)
// all 15 med3 are independent (each reads OLD neighbors) -> full pipelining
#define INS16(x) do{ \
    u32 _x = (x); \
    MED3(kk15, _x, kk14, kk15); MED3(kk14, _x, kk13, kk14); \
    MED3(kk13, _x, kk12, kk13); MED3(kk12, _x, kk11, kk12); \
    MED3(kk11, _x, kk10, kk11); MED3(kk10, _x, kk9,  kk10); \
    MED3(kk9,  _x, kk8,  kk9 ); MED3(kk8,  _x, kk7,  kk8 ); \
    MED3(kk7,  _x, kk6,  kk7 ); MED3(kk6,  _x, kk5,  kk6 ); \
    MED3(kk5,  _x, kk4,  kk5 ); MED3(kk4,  _x, kk3,  kk4 ); \
    MED3(kk3,  _x, kk2,  kk3 ); MED3(kk2,  _x, kk1,  kk2 ); \
    MED3(kk1,  _x, kk0,  kk1 ); kk0 = UMIN(_x, kk0); \
}while(0)

#define CEU32(a,b) { u32 _lo = UMIN(a,b); u32 _hi = (a)<(b)?(b):(a); (a)=_lo; (b)=_hi; }
// bitonic merge of 16 u32 (input bitonic -> ascending)
#define M16U(n0,n1,n2,n3,n4,n5,n6,n7,n8,n9,n10,n11,n12,n13,n14,n15) \
 CEU32(n0,n8) CEU32(n1,n9) CEU32(n2,n10) CEU32(n3,n11) CEU32(n4,n12) CEU32(n5,n13) CEU32(n6,n14) CEU32(n7,n15) \
 CEU32(n0,n4) CEU32(n1,n5) CEU32(n2,n6) CEU32(n3,n7) CEU32(n8,n12) CEU32(n9,n13) CEU32(n10,n14) CEU32(n11,n15) \
 CEU32(n0,n2) CEU32(n1,n3) CEU32(n4,n6) CEU32(n5,n7) CEU32(n8,n10) CEU32(n9,n11) CEU32(n12,n14) CEU32(n13,n15) \
 CEU32(n0,n1) CEU32(n2,n3) CEU32(n4,n5) CEU32(n6,n7) CEU32(n8,n9) CEU32(n10,n11) CEU32(n12,n13) CEU32(n14,n15)

// cross-lane merge: partner's list reversed, elementwise min, bitonic merge
#define MRGU(mm) do{ \
    u32 p0 =(u32)__shfl_xor((int)kk15,mm), p1 =(u32)__shfl_xor((int)kk14,mm); \
    u32 p2 =(u32)__shfl_xor((int)kk13,mm), p3 =(u32)__shfl_xor((int)kk12,mm); \
    u32 p4 =(u32)__shfl_xor((int)kk11,mm), p5 =(u32)__shfl_xor((int)kk10,mm); \
    u32 p6 =(u32)__shfl_xor((int)kk9, mm), p7 =(u32)__shfl_xor((int)kk8, mm); \
    u32 p8 =(u32)__shfl_xor((int)kk7, mm), p9 =(u32)__shfl_xor((int)kk6, mm); \
    u32 p10=(u32)__shfl_xor((int)kk5, mm), p11=(u32)__shfl_xor((int)kk4, mm); \
    u32 p12=(u32)__shfl_xor((int)kk3, mm), p13=(u32)__shfl_xor((int)kk2, mm); \
    u32 p14=(u32)__shfl_xor((int)kk1, mm), p15=(u32)__shfl_xor((int)kk0, mm); \
    kk0 =UMIN(kk0 ,p0 ); kk1 =UMIN(kk1 ,p1 ); kk2 =UMIN(kk2 ,p2 ); kk3 =UMIN(kk3 ,p3 ); \
    kk4 =UMIN(kk4 ,p4 ); kk5 =UMIN(kk5 ,p5 ); kk6 =UMIN(kk6 ,p6 ); kk7 =UMIN(kk7 ,p7 ); \
    kk8 =UMIN(kk8 ,p8 ); kk9 =UMIN(kk9 ,p9 ); kk10=UMIN(kk10,p10); kk11=UMIN(kk11,p11); \
    kk12=UMIN(kk12,p12); kk13=UMIN(kk13,p13); kk14=UMIN(kk14,p14); kk15=UMIN(kk15,p15); \
    M16U(kk0,kk1,kk2,kk3,kk4,kk5,kk6,kk7,kk8,kk9,kk10,kk11,kk12,kk13,kk14,kk15) \
}while(0)

#define OUTE8(e, kv) if (((e) & 7) == r) { \
    int _j = (int)((kv) & 1023u); \
    float4 _sj = s4[_j]; \
    float _dx = si.x-_sj.x, _dy = si.y-_sj.y, _dz = si.z-_sj.z, _dw = si.w-_sj.w; \
    float _d2 = _dx*_dx + _dy*_dy + _dz*_dz + _dw*_dw; \
    ew_out[bq + (e)] = expf(-10.0f * _d2); \
    idx_out[bq + (e)] = gbase + _j; }

// ---------------------------------------------------------------------------
// Kernel 2 v6: exact kNN (K=16). Branchless med3-insert selection.
// 32 queries/block (grid 2048 -> 32 waves/CU). lane = 8*grp + r; each lane
// scans 128 candidates (octant r), bank-staggered; 3-round shfl merge.
// ---------------------------------------------------------------------------
__global__ __launch_bounds__(256) void k2_knn(
    const float* __restrict__ s, int* __restrict__ idx_out, float* __restrict__ ew_out)
{
    __shared__ float4 s4[NPG];
    int tid = threadIdx.x;
    int g     = blockIdx.x >> 5;
    int gbase = g * NPG;
    int qblk  = (blockIdx.x & 31) * 32;
    const float4* sg = (const float4*)(s + (size_t)g*NPG*SPACE);
    for (int e = tid; e < NPG; e += 256) s4[e] = sg[e];
    __syncthreads();

    int lane = tid & 63;
    int grp  = lane >> 3;                   // 8 queries per wave
    int r    = lane & 7;                    // candidate octant
    int q    = qblk + (tid >> 6)*8 + grp;
    float4 si = s4[q];

    u32 kk0=~0u,kk1=~0u,kk2=~0u,kk3=~0u,kk4=~0u,kk5=~0u,kk6=~0u,kk7=~0u,
        kk8=~0u,kk9=~0u,kk10=~0u,kk11=~0u,kk12=~0u,kk13=~0u,kk14=~0u,kk15=~0u;

    int jb0 = r*128;
    #pragma unroll 2
    for (int it = 0; it < 128; ++it) {
        int j = jb0 + ((it + 3*r) & 127);   // 8 distinct banks per wave-instr
        float4 sj = s4[j];
        float dx = si.x-sj.x, dy = si.y-sj.y, dz = si.z-sj.z, dw = si.w-sj.w;
        float d2 = dx*dx + dy*dy + dz*dz + dw*dw;
        u32 key = (__float_as_uint(d2) & ~1023u) | (u32)j;
        key = (j == q) ? ~0u : key;         // exclude self
        INS16(key);
    }

    MRGU(1); MRGU(2); MRGU(4);              // merge 8 octant-top16s

    size_t bq = ((size_t)(gbase + q)) * KNN;
    OUTE8(0,kk0)  OUTE8(1,kk1)  OUTE8(2,kk2)   OUTE8(3,kk3)
    OUTE8(4,kk4)  OUTE8(5,kk5)  OUTE8(6,kk6)   OUTE8(7,kk7)
    OUTE8(8,kk8)  OUTE8(9,kk9)  OUTE8(10,kk10) OUTE8(11,kk11)
    OUTE8(12,kk12) OUTE8(13,kk13) OUTE8(14,kk14) OUTE8(15,kk15)
}

// ---------------------------------------------------------------------------
// Kernel 34 v2: fused aggregation + GEMM + BN partial stats.  (unchanged)
// ---------------------------------------------------------------------------
typedef __attribute__((ext_vector_type(8))) short bf16x8;
typedef __attribute__((ext_vector_type(4))) float f32x4;

__device__ __forceinline__ u32 pk2bf(float a, float b) {
    u32 ua = __float_as_uint(a);
    u32 ub = __float_as_uint(b);
    ua = (ua + 0x7fffu + ((ua >> 16) & 1u)) >> 16;
    ub = (ub + 0x7fffu + ((ub >> 16) & 1u)) >> 16;
    return (ua & 0xffffu) | (ub << 16);
}
__device__ __forceinline__ unsigned short bfr(float a) {
    u32 ua = __float_as_uint(a);
    ua = (ua + 0x7fffu + ((ua >> 16) & 1u)) >> 16;
    return (unsigned short)ua;
}

__global__ __launch_bounds__(256) void k34_agg_gemm(
    const float* __restrict__ x, const float* __restrict__ h,
    const float* __restrict__ z, const int* __restrict__ idx,
    const float* __restrict__ ew,
    const float* __restrict__ Wskip, const float* __restrict__ Wagg,
    const float* __restrict__ bagg, float* __restrict__ out,
    float* __restrict__ partial)
{
    __shared__ char AggL[64*512];   // [row][256 ch] bf16, swizzled, 32 KB
    __shared__ char Bl[128*128];    // weight chunk tile, 16 KB
    __shared__ float st[128], st2[128];
    int tid = threadIdx.x;
    int lane = tid & 63, wid = tid >> 6;
    int bid = blockIdx.x;
    int tile = (bid & 7) * 128 + (bid >> 3);   // XCD-chunked swizzle (1024%8==0)
    int mbase = tile * 64;

    if (tid < 128) { st[tid] = 0.f; st2[tid] = 0.f; }

    // ---- phase 0: aggregation (16 nodes per wave) ----
    #pragma unroll 2
    for (int t = 0; t < 16; ++t) {
        int row = wid*16 + t;
        int node = mbase + row;
        int kq = lane & 15;
        int jv = idx[(size_t)node*KNN + kq];
        float ev = ew[(size_t)node*KNN + kq];
        float dz = z[jv] - z[node];
        float as = fabsf(dz);
        as += __shfl_xor(as, 1); as += __shfl_xor(as, 2);
        as += __shfl_xor(as, 4); as += __shfl_xor(as, 8);
        float F = dz / (as + 1e-8f);
        float mean = 0.f, mx = -INFINITY, sm = 0.f, dv = 0.f;
        #pragma unroll
        for (int k = 0; k < KNN; ++k) {
            int   j = __shfl(jv, k);
            float e = __shfl(ev, k);
            float f = __shfl(F,  k);
            float hv = h[(size_t)j*PROP + lane];
            float m = hv * e;
            mean += m; mx = fmaxf(mx, m);
            sm += m * fabsf(f); dv += m * f;
        }
        int swz = (row & 7) << 4;
        char* rp = AggL + row*512;
        *(unsigned short*)(rp + ((2*(lane      )) ^ swz)) = bfr(mean * 0.0625f);
        *(unsigned short*)(rp + ((2*(lane +  64)) ^ swz)) = bfr(mx);
        *(unsigned short*)(rp + ((2*(lane + 128)) ^ swz)) = bfr(sm * 0.0625f);
        *(unsigned short*)(rp + ((2*(lane + 192)) ^ swz)) = bfr(dv);
    }

    // ---- phase 1: GEMM ----
    int wy = wid >> 1, wx = wid & 1;
    int colb = wx*64 + (lane & 15);
    f32x4 acc[2][4];
    #pragma unroll
    for (int nc = 0; nc < 4; ++nc) {
        float bv = bagg[colb + nc*16];
        #pragma unroll
        for (int mr = 0; mr < 2; ++mr) acc[mr][nc] = (f32x4){bv, bv, bv, bv};
    }

    int brow = tid >> 1, bkq = (tid & 1) * 32;
    int bsw = (brow & 7) << 4;

    for (int ch = 0; ch < 5; ++ch) {
        __syncthreads();   // phase-0 done / prev chunk's Bl reads done
        const float* bp = (ch == 0) ? (Wskip + (size_t)brow*64  + bkq)
                                    : (Wagg  + (size_t)brow*256 + (ch-1)*64 + bkq);
        #pragma unroll
        for (int g2 = 0; g2 < 4; ++g2) {
            float4 f0 = ((const float4*)bp)[2*g2], f1 = ((const float4*)bp)[2*g2+1];
            uint4 u = { pk2bf(f0.x,f0.y), pk2bf(f0.z,f0.w), pk2bf(f1.x,f1.y), pk2bf(f1.z,f1.w) };
            *(uint4*)(Bl + brow*128 + ((bkq*2 + g2*16) ^ bsw)) = u;
        }
        __syncthreads();

        #pragma unroll
        for (int ks = 0; ks < 2; ++ks) {
            int kb = ks*64 + ((lane >> 4) * 16);     // byte offset in 128B row
            bf16x8 af[2], bfrg[4];
            if (ch == 0) {
                // A-fragments straight from global x (f32 -> bf16)
                int ke = ks*32 + (lane >> 4)*8;      // element offset
                #pragma unroll
                for (int mr = 0; mr < 2; ++mr) {
                    int row = mbase + wy*32 + mr*16 + (lane & 15);
                    const float* xp = x + (size_t)row*64 + ke;
                    float4 f0 = *(const float4*)xp, f1 = *(const float4*)(xp + 4);
                    union { u32 u[4]; bf16x8 v; } cv;
                    cv.u[0] = pk2bf(f0.x,f0.y); cv.u[1] = pk2bf(f0.z,f0.w);
                    cv.u[2] = pk2bf(f1.x,f1.y); cv.u[3] = pk2bf(f1.z,f1.w);
                    af[mr] = cv.v;
                }
            } else {
                #pragma unroll
                for (int mr = 0; mr < 2; ++mr) {
                    int row = wy*32 + mr*16 + (lane & 15);
                    af[mr] = *(const bf16x8*)(AggL + row*512 + (ch-1)*128
                                              + (kb ^ ((row & 7) << 4)));
                }
            }
            #pragma unroll
            for (int nc = 0; nc < 4; ++nc) {
                int n = wx*64 + nc*16 + (lane & 15);
                bfrg[nc] = *(const bf16x8*)(Bl + n*128 + (kb ^ ((n & 7) << 4)));
            }
            #pragma unroll
            for (int mr = 0; mr < 2; ++mr)
                #pragma unroll
                for (int nc = 0; nc < 4; ++nc)
                    acc[mr][nc] = __builtin_amdgcn_mfma_f32_16x16x32_bf16(
                        af[mr], bfrg[nc], acc[mr][nc], 0, 0, 0);
        }
    }

    // ---- epilogue: store + per-channel BN partial stats ----
    float s1[4] = {0,0,0,0}, s2[4] = {0,0,0,0};
    #pragma unroll
    for (int mr = 0; mr < 2; ++mr) {
        int r0 = mbase + wy*32 + mr*16 + (lane >> 4)*4;
        #pragma unroll
        for (int nc = 0; nc < 4; ++nc) {
            int c = colb + nc*16;
            #pragma unroll
            for (int j = 0; j < 4; ++j) {
                float v = acc[mr][nc][j];
                out[(size_t)(r0 + j)*OUT_CH + c] = v;
                s1[nc] += v;
                s2[nc] += v*v;
            }
        }
    }
    #pragma unroll
    for (int nc = 0; nc < 4; ++nc) {
        s1[nc] += __shfl_xor(s1[nc], 16); s1[nc] += __shfl_xor(s1[nc], 32);
        s2[nc] += __shfl_xor(s2[nc], 16); s2[nc] += __shfl_xor(s2[nc], 32);
    }
    __syncthreads();
    if ((lane >> 4) == 0) {
        #pragma unroll
        for (int nc = 0; nc < 4; ++nc) {
            atomicAdd(&st[colb + nc*16],  s1[nc]);
            atomicAdd(&st2[colb + nc*16], s2[nc]);
        }
    }
    __syncthreads();
    if (tid < 128) {
        partial[(size_t)bid*256 + tid]       = st[tid];
        partial[(size_t)bid*256 + 128 + tid] = st2[tid];
    }
}

// ---------------------------------------------------------------------------
// Kernel 5r: reduce 1024 block-partials -> sums[256]
// ---------------------------------------------------------------------------
__global__ __launch_bounds__(256) void k5_red(
    const float* __restrict__ partial, float* __restrict__ sums)
{
    int c = threadIdx.x;
    int b0 = blockIdx.x * 32;
    float acc = 0.f;
    #pragma unroll 8
    for (int b = 0; b < 32; ++b)
        acc += partial[(size_t)(b0 + b)*256 + c];
    atomicAdd(&sums[c], acc);
}

// ---------------------------------------------------------------------------
// Kernel 6: BatchNorm (training stats, biased var) + ReLU, in place on d_out
// ---------------------------------------------------------------------------
__global__ __launch_bounds__(256) void k6_bn(
    float* __restrict__ out, const float* __restrict__ sums,
    const float* __restrict__ gamma, const float* __restrict__ beta)
{
    int f = blockIdx.x*256 + threadIdx.x;     // float4 index
    float4 v = *(float4*)(out + (size_t)f*4);
    int o0 = (f*4) & 127;
    const float invN = 1.f / (float)NTOT;
    float r[4] = {v.x, v.y, v.z, v.w};
    #pragma unroll
    for (int c = 0; c < 4; c++) {
        int o = o0 + c;
        float mu  = sums[o] * invN;
        float var = sums[128+o] * invN - mu*mu;
        float sc  = gamma[o] * rsqrtf(var + 1e-5f);
        float sh  = beta[o] - mu*sc;
        float y = r[c]*sc + sh;
        r[c] = y > 0.f ? y : 0.f;
    }
    *(float4*)(out + (size_t)f*4) = make_float4(r[0], r[1], r[2], r[3]);
}

// ---------------------------------------------------------------------------
extern "C" void kernel_launch(void* const* d_in, const int* in_sizes, int n_in,
                              void* d_out, int out_size, void* d_ws, size_t ws_size,
                              hipStream_t stream)
{
    (void)in_sizes; (void)n_in; (void)out_size; (void)ws_size;
    const float* x     = (const float*)d_in[0];
    const float* z     = (const float*)d_in[1];
    /* d_in[2] = batch (int32) — graphs are fixed contiguous blocks, unused */
    const float* Ws    = (const float*)d_in[3];
    const float* bs    = (const float*)d_in[4];
    const float* Wh    = (const float*)d_in[5];
    const float* bh    = (const float*)d_in[6];
    const float* Wskip = (const float*)d_in[7];
    const float* Wagg  = (const float*)d_in[8];
    const float* bagg  = (const float*)d_in[9];
    const float* gamma = (const float*)d_in[10];
    const float* beta  = (const float*)d_in[11];
    float* out = (float*)d_out;

    const size_t N = NTOT;
    float* ws   = (float*)d_ws;
    float* sbuf = ws;                        // N*4
    float* hbuf = sbuf + N*4;                // N*64
    int*   idxb = (int*)(hbuf + N*64);       // N*16 int32
    float* ewb  = (float*)(idxb + N*16);     // N*16
    float* part = ewb + N*16;                // 1024*256
    float* sums = part + 1024*256;           // 256

    hipMemsetAsync(sums, 0, 256*sizeof(float), stream);
    k1_proj<<<NTOT/256, 256, 0, stream>>>(x, Ws, bs, Wh, bh, sbuf, hbuf);
    k2_knn <<<NGRAPH*32, 256, 0, stream>>>(sbuf, idxb, ewb);
    k34_agg_gemm<<<NTOT/64, 256, 0, stream>>>(x, hbuf, z, idxb, ewb,
                                              Wskip, Wagg, bagg, out, part);
    k5_red<<<32, 256, 0, stream>>>(part, sums);
    k6_bn <<<NTOT*OUT_CH/4/256, 256, 0, stream>>>(out, sums, gamma, beta);
}

// Round 10
// 265.362 us; speedup vs baseline: 2.8350x; 1.0138x over previous
//
#include <hip/hip_runtime.h>
#include <hip/hip_bf16.h>
#include <math.h>

#define NPG   1024
#define KNN   16
#define IN_CH 64
#define OUT_CH 128
#define SPACE 4
#define PROP  64
#define NGRAPH 64
#define NTOT  (NGRAPH*NPG)   // 65536

typedef unsigned long long u64;
typedef unsigned int u32;
typedef unsigned short u16;

// ---------------------------------------------------------------------------
// Kernel 1: s = x@Ws.T + bs ; h = x@Wh.T + bh   (thread per node)
// ---------------------------------------------------------------------------
__global__ __launch_bounds__(256) void k1_proj(
    const float* __restrict__ x, const float* __restrict__ Ws, const float* __restrict__ bs,
    const float* __restrict__ Wh, const float* __restrict__ bh,
    float* __restrict__ s_out, float* __restrict__ h_out)
{
    __shared__ float whl[PROP*IN_CH];   // [p][c]
    __shared__ float wsl[SPACE*IN_CH];  // [d][c]
    int tid = threadIdx.x;
    {
        const float4* src = (const float4*)Wh;
        float4* dst = (float4*)whl;
        for (int e = tid; e < PROP*IN_CH/4; e += 256) dst[e] = src[e];
        if (tid < SPACE*IN_CH/4) ((float4*)wsl)[tid] = ((const float4*)Ws)[tid];
    }
    __syncthreads();
    int i = blockIdx.x*256 + tid;

    float4 xr[16];
    const float4* xrow = (const float4*)(x + (size_t)i*IN_CH);
    #pragma unroll
    for (int q = 0; q < 16; q++) xr[q] = xrow[q];

    #pragma unroll
    for (int d = 0; d < SPACE; d++) {
        float acc = bs[d];
        const float4* wr = (const float4*)(wsl + d*IN_CH);
        #pragma unroll
        for (int q = 0; q < 16; q++) {
            float4 w = wr[q];
            acc += xr[q].x*w.x + xr[q].y*w.y + xr[q].z*w.z + xr[q].w*w.w;
        }
        s_out[(size_t)i*SPACE + d] = acc;
    }
    #pragma unroll 4
    for (int p = 0; p < PROP; p++) {
        float acc = bh[p];
        const float4* wr = (const float4*)(whl + p*IN_CH);
        #pragma unroll
        for (int q = 0; q < 16; q++) {
            float4 w = wr[q];
            acc += xr[q].x*w.x + xr[q].y*w.y + xr[q].z*w.z + xr[q].w*w.w;
        }
        h_out[(size_t)i*PROP + p] = acc;
    }
}

// ---------------------------------------------------------------------------
// k2 v6 primitives: u32 keys, branchless med3 sorted-insert, bitonic merge.
// key = (float_bits(d2) & ~1023) | j   -- d2>=0 so bits are u32-monotone;
// low 10 bits = j reproduce lax.top_k's smallest-index tie-break.
// ---------------------------------------------------------------------------
#define MED3(d, x, a, b) asm("v_med3_u32 %0, %1, %2, %3" : "=v"(d) : "v"(x), "v"(a), "v"(b))
#define UMIN(a,b) ((a)<(b)?(a):(b))

// branchless sorted insert (list ascending kk0..kk15, kk15 = worst, dropped)
// all 15 med3 are independent (each reads OLD neighbors) -> full pipelining
#define INS16(x) do{ \
    u32 _x = (x); \
    MED3(kk15, _x, kk14, kk15); MED3(kk14, _x, kk13, kk14); \
    MED3(kk13, _x, kk12, kk13); MED3(kk12, _x, kk11, kk12); \
    MED3(kk11, _x, kk10, kk11); MED3(kk10, _x, kk9,  kk10); \
    MED3(kk9,  _x, kk8,  kk9 ); MED3(kk8,  _x, kk7,  kk8 ); \
    MED3(kk7,  _x, kk6,  kk7 ); MED3(kk6,  _x, kk5,  kk6 ); \
    MED3(kk5,  _x, kk4,  kk5 ); MED3(kk4,  _x, kk3,  kk4 ); \
    MED3(kk3,  _x, kk2,  kk3 ); MED3(kk2,  _x, kk1,  kk2 ); \
    MED3(kk1,  _x, kk0,  kk1 ); kk0 = UMIN(_x, kk0); \
}while(0)

#define CEU32(a,b) { u32 _lo = UMIN(a,b); u32 _hi = (a)<(b)?(b):(a); (a)=_lo; (b)=_hi; }
// bitonic merge of 16 u32 (input bitonic -> ascending)
#define M16U(n0,n1,n2,n3,n4,n5,n6,n7,n8,n9,n10,n11,n12,n13,n14,n15) \
 CEU32(n0,n8) CEU32(n1,n9) CEU32(n2,n10) CEU32(n3,n11) CEU32(n4,n12) CEU32(n5,n13) CEU32(n6,n14) CEU32(n7,n15) \
 CEU32(n0,n4) CEU32(n1,n5) CEU32(n2,n6) CEU32(n3,n7) CEU32(n8,n12) CEU32(n9,n13) CEU32(n10,n14) CEU32(n11,n15) \
 CEU32(n0,n2) CEU32(n1,n3) CEU32(n4,n6) CEU32(n5,n7) CEU32(n8,n10) CEU32(n9,n11) CEU32(n12,n14) CEU32(n13,n15) \
 CEU32(n0,n1) CEU32(n2,n3) CEU32(n4,n5) CEU32(n6,n7) CEU32(n8,n9) CEU32(n10,n11) CEU32(n12,n13) CEU32(n14,n15)

// cross-lane merge: partner's list reversed, elementwise min, bitonic merge
#define MRGU(mm) do{ \
    u32 p0 =(u32)__shfl_xor((int)kk15,mm), p1 =(u32)__shfl_xor((int)kk14,mm); \
    u32 p2 =(u32)__shfl_xor((int)kk13,mm), p3 =(u32)__shfl_xor((int)kk12,mm); \
    u32 p4 =(u32)__shfl_xor((int)kk11,mm), p5 =(u32)__shfl_xor((int)kk10,mm); \
    u32 p6 =(u32)__shfl_xor((int)kk9, mm), p7 =(u32)__shfl_xor((int)kk8, mm); \
    u32 p8 =(u32)__shfl_xor((int)kk7, mm), p9 =(u32)__shfl_xor((int)kk6, mm); \
    u32 p10=(u32)__shfl_xor((int)kk5, mm), p11=(u32)__shfl_xor((int)kk4, mm); \
    u32 p12=(u32)__shfl_xor((int)kk3, mm), p13=(u32)__shfl_xor((int)kk2, mm); \
    u32 p14=(u32)__shfl_xor((int)kk1, mm), p15=(u32)__shfl_xor((int)kk0, mm); \
    kk0 =UMIN(kk0 ,p0 ); kk1 =UMIN(kk1 ,p1 ); kk2 =UMIN(kk2 ,p2 ); kk3 =UMIN(kk3 ,p3 ); \
    kk4 =UMIN(kk4 ,p4 ); kk5 =UMIN(kk5 ,p5 ); kk6 =UMIN(kk6 ,p6 ); kk7 =UMIN(kk7 ,p7 ); \
    kk8 =UMIN(kk8 ,p8 ); kk9 =UMIN(kk9 ,p9 ); kk10=UMIN(kk10,p10); kk11=UMIN(kk11,p11); \
    kk12=UMIN(kk12,p12); kk13=UMIN(kk13,p13); kk14=UMIN(kk14,p14); kk15=UMIN(kk15,p15); \
    M16U(kk0,kk1,kk2,kk3,kk4,kk5,kk6,kk7,kk8,kk9,kk10,kk11,kk12,kk13,kk14,kk15) \
}while(0)

#define OUTE8(e, kv) if (((e) & 7) == r) { \
    int _j = (int)((kv) & 1023u); \
    float4 _sj = s4[_j]; \
    float _dx = si.x-_sj.x, _dy = si.y-_sj.y, _dz = si.z-_sj.z, _dw = si.w-_sj.w; \
    float _d2 = _dx*_dx + _dy*_dy + _dz*_dz + _dw*_dw; \
    ew_out[bq + (e)] = expf(-10.0f * _d2); \
    idx_out[bq + (e)] = gbase + _j; }

// ---------------------------------------------------------------------------
// Kernel 2 v6: exact kNN (K=16). Branchless med3-insert selection.
// 32 queries/block (grid 2048 -> 32 waves/CU). lane = 8*grp + r; each lane
// scans 128 candidates (octant r), bank-staggered; 3-round shfl merge.
// ---------------------------------------------------------------------------
__global__ __launch_bounds__(256) void k2_knn(
    const float* __restrict__ s, int* __restrict__ idx_out, float* __restrict__ ew_out)
{
    __shared__ float4 s4[NPG];
    int tid = threadIdx.x;
    int g     = blockIdx.x >> 5;
    int gbase = g * NPG;
    int qblk  = (blockIdx.x & 31) * 32;
    const float4* sg = (const float4*)(s + (size_t)g*NPG*SPACE);
    for (int e = tid; e < NPG; e += 256) s4[e] = sg[e];
    __syncthreads();

    int lane = tid & 63;
    int grp  = lane >> 3;                   // 8 queries per wave
    int r    = lane & 7;                    // candidate octant
    int q    = qblk + (tid >> 6)*8 + grp;
    float4 si = s4[q];

    u32 kk0=~0u,kk1=~0u,kk2=~0u,kk3=~0u,kk4=~0u,kk5=~0u,kk6=~0u,kk7=~0u,
        kk8=~0u,kk9=~0u,kk10=~0u,kk11=~0u,kk12=~0u,kk13=~0u,kk14=~0u,kk15=~0u;

    int jb0 = r*128;
    #pragma unroll 2
    for (int it = 0; it < 128; ++it) {
        int j = jb0 + ((it + 3*r) & 127);   // 8 distinct banks per wave-instr
        float4 sj = s4[j];
        float dx = si.x-sj.x, dy = si.y-sj.y, dz = si.z-sj.z, dw = si.w-sj.w;
        float d2 = dx*dx + dy*dy + dz*dz + dw*dw;
        u32 key = (__float_as_uint(d2) & ~1023u) | (u32)j;
        key = (j == q) ? ~0u : key;         // exclude self
        INS16(key);
    }

    MRGU(1); MRGU(2); MRGU(4);              // merge 8 octant-top16s

    size_t bq = ((size_t)(gbase + q)) * KNN;
    OUTE8(0,kk0)  OUTE8(1,kk1)  OUTE8(2,kk2)   OUTE8(3,kk3)
    OUTE8(4,kk4)  OUTE8(5,kk5)  OUTE8(6,kk6)   OUTE8(7,kk7)
    OUTE8(8,kk8)  OUTE8(9,kk9)  OUTE8(10,kk10) OUTE8(11,kk11)
    OUTE8(12,kk12) OUTE8(13,kk13) OUTE8(14,kk14) OUTE8(15,kk15)
}

// ---------------------------------------------------------------------------
// shared helpers for bf16 conversion
// ---------------------------------------------------------------------------
typedef __attribute__((ext_vector_type(8))) short bf16x8;
typedef __attribute__((ext_vector_type(4))) float f32x4;

__device__ __forceinline__ u32 pk2bf(float a, float b) {
    u32 ua = __float_as_uint(a);
    u32 ub = __float_as_uint(b);
    ua = (ua + 0x7fffu + ((ua >> 16) & 1u)) >> 16;
    ub = (ub + 0x7fffu + ((ub >> 16) & 1u)) >> 16;
    return (ua & 0xffffu) | (ub << 16);
}
__device__ __forceinline__ u16 bfr(float a) {
    u32 ua = __float_as_uint(a);
    ua = (ua + 0x7fffu + ((ua >> 16) & 1u)) >> 16;
    return (u16)ua;
}

// ---------------------------------------------------------------------------
// Kernel 3 v3: standalone aggregation, wave-per-node, NO LDS -> full
// occupancy. Writes agg as bf16 row-major [N][256] (coalesced 2B stores).
// Identical arithmetic to the fused version (same bf16 rounding point).
// ---------------------------------------------------------------------------
__global__ __launch_bounds__(256) void k3_agg(
    const float* __restrict__ h, const float* __restrict__ z,
    const int* __restrict__ idx, const float* __restrict__ ew,
    u16* __restrict__ agg16)
{
    int tid = threadIdx.x;
    int lane = tid & 63;
    int i = blockIdx.x*4 + (tid >> 6);
    float zi = z[i];

    int   kq = lane & 15;
    int   jv = idx[(size_t)i*KNN + kq];
    float ev = ew[(size_t)i*KNN + kq];
    float dz = z[jv] - zi;
    float as = fabsf(dz);
    as += __shfl_xor(as, 1); as += __shfl_xor(as, 2);
    as += __shfl_xor(as, 4); as += __shfl_xor(as, 8);
    float F = dz / (as + 1e-8f);

    float mean = 0.f, mx = -INFINITY, sm = 0.f, dv = 0.f;
    #pragma unroll
    for (int k = 0; k < KNN; ++k) {
        int   j = __shfl(jv, k);
        float e = __shfl(ev, k);
        float f = __shfl(F,  k);
        float hv = h[(size_t)j*PROP + lane];   // 256B coalesced, L2-resident
        float m = hv * e;
        mean += m; mx = fmaxf(mx, m);
        sm += m * fabsf(f); dv += m * f;
    }
    u16* ap = agg16 + (size_t)i*256;
    ap[lane]       = bfr(mean * 0.0625f);
    ap[64 + lane]  = bfr(mx);
    ap[128 + lane] = bfr(sm * 0.0625f);
    ap[192 + lane] = bfr(dv);
}

// ---------------------------------------------------------------------------
// Kernel 4 v3: pure GEMM  out = x@Wskip.T + agg@Wagg.T + bagg  (bf16 MFMA).
// BM=64, BN=128, 5 K-chunks of 64. Uniform 8KB swizzled A-tile per chunk
// (ch0: cvt from f32 x; ch1-4: raw copy from bf16 agg). 16KB B-tile.
// LDS 25KB -> 6 blocks/CU. BN-stats partials epilogue (no global atomics).
// ---------------------------------------------------------------------------
__global__ __launch_bounds__(256) void k4_gemm(
    const float* __restrict__ x, const u16* __restrict__ agg16,
    const float* __restrict__ Wskip, const float* __restrict__ Wagg,
    const float* __restrict__ bagg, float* __restrict__ out,
    float* __restrict__ partial)
{
    __shared__ char Atl[64*128];    // 8KB  [row][64ch] bf16, swizzled
    __shared__ char Bl[128*128];    // 16KB [n][64ch]  bf16, swizzled
    __shared__ float st[128], st2[128];
    int tid = threadIdx.x;
    int lane = tid & 63, wid = tid >> 6;
    int bid = blockIdx.x;
    int mbase = bid * 64;

    if (tid < 128) { st[tid] = 0.f; st2[tid] = 0.f; }

    int wy = wid >> 1, wx = wid & 1;
    int colb = wx*64 + (lane & 15);
    f32x4 acc[2][4];
    #pragma unroll
    for (int nc = 0; nc < 4; ++nc) {
        float bv = bagg[colb + nc*16];
        #pragma unroll
        for (int mr = 0; mr < 2; ++mr) acc[mr][nc] = (f32x4){bv, bv, bv, bv};
    }

    int arow = tid >> 2, aseg = (tid & 3) * 16;    // A: 16 ch per thread
    int asw  = (arow & 7) << 4;
    int brow = tid >> 1, bkq = (tid & 1) * 32;     // B: 32 ch per thread
    int bsw  = (brow & 7) << 4;

    for (int ch = 0; ch < 5; ++ch) {
        __syncthreads();   // previous chunk's tile reads done
        // ---- stage A tile (64 rows x 64 ch bf16) ----
        if (ch == 0) {
            const float* ap = x + (size_t)(mbase + arow)*64 + aseg;
            float4 f0 = ((const float4*)ap)[0], f1 = ((const float4*)ap)[1];
            float4 f2 = ((const float4*)ap)[2], f3 = ((const float4*)ap)[3];
            uint4 u0 = { pk2bf(f0.x,f0.y), pk2bf(f0.z,f0.w), pk2bf(f1.x,f1.y), pk2bf(f1.z,f1.w) };
            uint4 u1 = { pk2bf(f2.x,f2.y), pk2bf(f2.z,f2.w), pk2bf(f3.x,f3.y), pk2bf(f3.z,f3.w) };
            *(uint4*)(Atl + arow*128 + ((aseg*2     ) ^ asw)) = u0;
            *(uint4*)(Atl + arow*128 + ((aseg*2 + 16) ^ asw)) = u1;
        } else {
            const u16* ap = agg16 + (size_t)(mbase + arow)*256 + (ch-1)*64 + aseg;
            uint4 u0 = ((const uint4*)ap)[0];
            uint4 u1 = ((const uint4*)ap)[1];
            *(uint4*)(Atl + arow*128 + ((aseg*2     ) ^ asw)) = u0;
            *(uint4*)(Atl + arow*128 + ((aseg*2 + 16) ^ asw)) = u1;
        }
        // ---- stage B tile (128 n x 64 ch bf16, cvt from f32 W) ----
        const float* bp = (ch == 0) ? (Wskip + (size_t)brow*64  + bkq)
                                    : (Wagg  + (size_t)brow*256 + (ch-1)*64 + bkq);
        #pragma unroll
        for (int g2 = 0; g2 < 4; ++g2) {
            float4 f0 = ((const float4*)bp)[2*g2], f1 = ((const float4*)bp)[2*g2+1];
            uint4 u = { pk2bf(f0.x,f0.y), pk2bf(f0.z,f0.w), pk2bf(f1.x,f1.y), pk2bf(f1.z,f1.w) };
            *(uint4*)(Bl + brow*128 + ((bkq*2 + g2*16) ^ bsw)) = u;
        }
        __syncthreads();

        #pragma unroll
        for (int ks = 0; ks < 2; ++ks) {
            int kb = ks*64 + ((lane >> 4) * 16);   // byte offset in 128B row
            bf16x8 af[2], bfrg[4];
            #pragma unroll
            for (int mr = 0; mr < 2; ++mr) {
                int row = wy*32 + mr*16 + (lane & 15);
                af[mr] = *(const bf16x8*)(Atl + row*128 + (kb ^ ((row & 7) << 4)));
            }
            #pragma unroll
            for (int nc = 0; nc < 4; ++nc) {
                int n = wx*64 + nc*16 + (lane & 15);
                bfrg[nc] = *(const bf16x8*)(Bl + n*128 + (kb ^ ((n & 7) << 4)));
            }
            #pragma unroll
            for (int mr = 0; mr < 2; ++mr)
                #pragma unroll
                for (int nc = 0; nc < 4; ++nc)
                    acc[mr][nc] = __builtin_amdgcn_mfma_f32_16x16x32_bf16(
                        af[mr], bfrg[nc], acc[mr][nc], 0, 0, 0);
        }
    }

    // ---- epilogue: store + per-channel BN partial stats ----
    float s1[4] = {0,0,0,0}, s2[4] = {0,0,0,0};
    #pragma unroll
    for (int mr = 0; mr < 2; ++mr) {
        int r0 = mbase + wy*32 + mr*16 + (lane >> 4)*4;
        #pragma unroll
        for (int nc = 0; nc < 4; ++nc) {
            int c = colb + nc*16;
            #pragma unroll
            for (int j = 0; j < 4; ++j) {
                float v = acc[mr][nc][j];
                out[(size_t)(r0 + j)*OUT_CH + c] = v;
                s1[nc] += v;
                s2[nc] += v*v;
            }
        }
    }
    #pragma unroll
    for (int nc = 0; nc < 4; ++nc) {
        s1[nc] += __shfl_xor(s1[nc], 16); s1[nc] += __shfl_xor(s1[nc], 32);
        s2[nc] += __shfl_xor(s2[nc], 16); s2[nc] += __shfl_xor(s2[nc], 32);
    }
    __syncthreads();
    if ((lane >> 4) == 0) {
        #pragma unroll
        for (int nc = 0; nc < 4; ++nc) {
            atomicAdd(&st[colb + nc*16],  s1[nc]);
            atomicAdd(&st2[colb + nc*16], s2[nc]);
        }
    }
    __syncthreads();
    if (tid < 128) {
        partial[(size_t)bid*256 + tid]       = st[tid];
        partial[(size_t)bid*256 + 128 + tid] = st2[tid];
    }
}

// ---------------------------------------------------------------------------
// Kernel 5r: reduce 1024 block-partials -> sums[256]
// ---------------------------------------------------------------------------
__global__ __launch_bounds__(256) void k5_red(
    const float* __restrict__ partial, float* __restrict__ sums)
{
    int c = threadIdx.x;
    int b0 = blockIdx.x * 32;
    float acc = 0.f;
    #pragma unroll 8
    for (int b = 0; b < 32; ++b)
        acc += partial[(size_t)(b0 + b)*256 + c];
    atomicAdd(&sums[c], acc);
}

// ---------------------------------------------------------------------------
// Kernel 6: BatchNorm (training stats, biased var) + ReLU, in place on d_out
// ---------------------------------------------------------------------------
__global__ __launch_bounds__(256) void k6_bn(
    float* __restrict__ out, const float* __restrict__ sums,
    const float* __restrict__ gamma, const float* __restrict__ beta)
{
    int f = blockIdx.x*256 + threadIdx.x;     // float4 index
    float4 v = *(float4*)(out + (size_t)f*4);
    int o0 = (f*4) & 127;
    const float invN = 1.f / (float)NTOT;
    float r[4] = {v.x, v.y, v.z, v.w};
    #pragma unroll
    for (int c = 0; c < 4; c++) {
        int o = o0 + c;
        float mu  = sums[o] * invN;
        float var = sums[128+o] * invN - mu*mu;
        float sc  = gamma[o] * rsqrtf(var + 1e-5f);
        float sh  = beta[o] - mu*sc;
        float y = r[c]*sc + sh;
        r[c] = y > 0.f ? y : 0.f;
    }
    *(float4*)(out + (size_t)f*4) = make_float4(r[0], r[1], r[2], r[3]);
}

// ---------------------------------------------------------------------------
extern "C" void kernel_launch(void* const* d_in, const int* in_sizes, int n_in,
                              void* d_out, int out_size, void* d_ws, size_t ws_size,
                              hipStream_t stream)
{
    (void)in_sizes; (void)n_in; (void)out_size; (void)ws_size;
    const float* x     = (const float*)d_in[0];
    const float* z     = (const float*)d_in[1];
    /* d_in[2] = batch (int32) — graphs are fixed contiguous blocks, unused */
    const float* Ws    = (const float*)d_in[3];
    const float* bs    = (const float*)d_in[4];
    const float* Wh    = (const float*)d_in[5];
    const float* bh    = (const float*)d_in[6];
    const float* Wskip = (const float*)d_in[7];
    const float* Wagg  = (const float*)d_in[8];
    const float* bagg  = (const float*)d_in[9];
    const float* gamma = (const float*)d_in[10];
    const float* beta  = (const float*)d_in[11];
    float* out = (float*)d_out;

    const size_t N = NTOT;
    float* ws    = (float*)d_ws;
    float* sbuf  = ws;                        // N*4 f32
    float* hbuf  = sbuf + N*4;                // N*64 f32
    int*   idxb  = (int*)(hbuf + N*64);       // N*16 int32
    float* ewb   = (float*)(idxb + N*16);     // N*16 f32
    u16*   agg16 = (u16*)(ewb + N*16);        // N*256 bf16 (N*128 f32 slots)
    float* part  = (float*)(agg16 + N*256);   // 1024*256 f32
    float* sums  = part + 1024*256;           // 256 f32

    hipMemsetAsync(sums, 0, 256*sizeof(float), stream);
    k1_proj<<<NTOT/256, 256, 0, stream>>>(x, Ws, bs, Wh, bh, sbuf, hbuf);
    k2_knn <<<NGRAPH*32, 256, 0, stream>>>(sbuf, idxb, ewb);
    k3_agg <<<NTOT/4,   256, 0, stream>>>(hbuf, z, idxb, ewb, agg16);
    k4_gemm<<<NTOT/64,  256, 0, stream>>>(x, agg16, Wskip, Wagg, bagg, out, part);
    k5_red <<<32, 256, 0, stream>>>(part, sums);
    k6_bn  <<<NTOT*OUT_CH/4/256, 256, 0, stream>>>(out, sums, gamma, beta);
}

// Round 11
// 260.674 us; speedup vs baseline: 2.8859x; 1.0180x over previous
//
#include <hip/hip_runtime.h>
#include <hip/hip_bf16.h>
#include <math.h>

#define NPG   1024
#define KNN   16
#define IN_CH 64
#define OUT_CH 128
#define SPACE 4
#define PROP  64
#define NGRAPH 64
#define NTOT  (NGRAPH*NPG)   // 65536

typedef unsigned long long u64;
typedef unsigned int u32;
typedef unsigned short u16;

// ---------------------------------------------------------------------------
// bf16 helpers (RNE) — same rounding everywhere, keeps output bit-identical
// ---------------------------------------------------------------------------
__device__ __forceinline__ u32 pk2bf(float a, float b) {
    u32 ua = __float_as_uint(a);
    u32 ub = __float_as_uint(b);
    ua = (ua + 0x7fffu + ((ua >> 16) & 1u)) >> 16;
    ub = (ub + 0x7fffu + ((ub >> 16) & 1u)) >> 16;
    return (ua & 0xffffu) | (ub << 16);
}
__device__ __forceinline__ u16 bfr(float a) {
    u32 ua = __float_as_uint(a);
    ua = (ua + 0x7fffu + ((ua >> 16) & 1u)) >> 16;
    return (u16)ua;
}

// ---------------------------------------------------------------------------
// Kernel 1: s = x@Ws.T + bs ; h = x@Wh.T + bh (thread per node) + extras:
//   - writes x16 (bf16 copy of x) for k4's A-chunk0
//   - blocks 256/257: convert Wskip/Wagg -> bf16, zero sums
// ---------------------------------------------------------------------------
__global__ __launch_bounds__(256) void k1_proj(
    const float* __restrict__ x, const float* __restrict__ Ws, const float* __restrict__ bs,
    const float* __restrict__ Wh, const float* __restrict__ bh,
    const float* __restrict__ Wskip, const float* __restrict__ Wagg,
    float* __restrict__ s_out, float* __restrict__ h_out, u16* __restrict__ x16,
    u16* __restrict__ wsk16, u16* __restrict__ wag16, float* __restrict__ sums)
{
    int tid = threadIdx.x;
    int bid = blockIdx.x;
    if (bid >= NTOT/256) {                  // weight-conversion tail blocks
        if (bid == NTOT/256) {
            sums[tid] = 0.f;
            for (int e4 = tid; e4 < OUT_CH*IN_CH/4; e4 += 256) {
                float4 v = ((const float4*)Wskip)[e4];
                uint2 u; u.x = pk2bf(v.x, v.y); u.y = pk2bf(v.z, v.w);
                ((uint2*)wsk16)[e4] = u;
            }
        } else {
            for (int e4 = tid; e4 < OUT_CH*4*PROP/4; e4 += 256) {
                float4 v = ((const float4*)Wagg)[e4];
                uint2 u; u.x = pk2bf(v.x, v.y); u.y = pk2bf(v.z, v.w);
                ((uint2*)wag16)[e4] = u;
            }
        }
        return;
    }

    __shared__ float whl[PROP*IN_CH];   // [p][c]
    __shared__ float wsl[SPACE*IN_CH];  // [d][c]
    {
        const float4* src = (const float4*)Wh;
        float4* dst = (float4*)whl;
        for (int e = tid; e < PROP*IN_CH/4; e += 256) dst[e] = src[e];
        if (tid < SPACE*IN_CH/4) ((float4*)wsl)[tid] = ((const float4*)Ws)[tid];
    }
    __syncthreads();
    int i = bid*256 + tid;

    float4 xr[16];
    const float4* xrow = (const float4*)(x + (size_t)i*IN_CH);
    #pragma unroll
    for (int q = 0; q < 16; q++) xr[q] = xrow[q];

    // bf16 copy of x for k4
    {
        uint4* xd = (uint4*)(x16 + (size_t)i*IN_CH);
        #pragma unroll
        for (int q = 0; q < 8; ++q) {
            uint4 u;
            u.x = pk2bf(xr[2*q].x,   xr[2*q].y);
            u.y = pk2bf(xr[2*q].z,   xr[2*q].w);
            u.z = pk2bf(xr[2*q+1].x, xr[2*q+1].y);
            u.w = pk2bf(xr[2*q+1].z, xr[2*q+1].w);
            xd[q] = u;
        }
    }

    #pragma unroll
    for (int d = 0; d < SPACE; d++) {
        float acc = bs[d];
        const float4* wr = (const float4*)(wsl + d*IN_CH);
        #pragma unroll
        for (int q = 0; q < 16; q++) {
            float4 w = wr[q];
            acc += xr[q].x*w.x + xr[q].y*w.y + xr[q].z*w.z + xr[q].w*w.w;
        }
        s_out[(size_t)i*SPACE + d] = acc;
    }
    #pragma unroll 4
    for (int p = 0; p < PROP; p++) {
        float acc = bh[p];
        const float4* wr = (const float4*)(whl + p*IN_CH);
        #pragma unroll
        for (int q = 0; q < 16; q++) {
            float4 w = wr[q];
            acc += xr[q].x*w.x + xr[q].y*w.y + xr[q].z*w.z + xr[q].w*w.w;
        }
        h_out[(size_t)i*PROP + p] = acc;
    }
}

// ---------------------------------------------------------------------------
// k2 primitives: u32 keys, branchless med3 sorted-insert, bitonic merge.
// key = (float_bits(d2) & ~1023) | j
// ---------------------------------------------------------------------------
#define MED3(d, x, a, b) asm("v_med3_u32 %0, %1, %2, %3" : "=v"(d) : "v"(x), "v"(a), "v"(b))
#define UMIN(a,b) ((a)<(b)?(a):(b))

#define INS16(x) do{ \
    u32 _x = (x); \
    MED3(kk15, _x, kk14, kk15); MED3(kk14, _x, kk13, kk14); \
    MED3(kk13, _x, kk12, kk13); MED3(kk12, _x, kk11, kk12); \
    MED3(kk11, _x, kk10, kk11); MED3(kk10, _x, kk9,  kk10); \
    MED3(kk9,  _x, kk8,  kk9 ); MED3(kk8,  _x, kk7,  kk8 ); \
    MED3(kk7,  _x, kk6,  kk7 ); MED3(kk6,  _x, kk5,  kk6 ); \
    MED3(kk5,  _x, kk4,  kk5 ); MED3(kk4,  _x, kk3,  kk4 ); \
    MED3(kk3,  _x, kk2,  kk3 ); MED3(kk2,  _x, kk1,  kk2 ); \
    MED3(kk1,  _x, kk0,  kk1 ); kk0 = UMIN(_x, kk0); \
}while(0)

#define CEU32(a,b) { u32 _lo = UMIN(a,b); u32 _hi = (a)<(b)?(b):(a); (a)=_lo; (b)=_hi; }
#define M16U(n0,n1,n2,n3,n4,n5,n6,n7,n8,n9,n10,n11,n12,n13,n14,n15) \
 CEU32(n0,n8) CEU32(n1,n9) CEU32(n2,n10) CEU32(n3,n11) CEU32(n4,n12) CEU32(n5,n13) CEU32(n6,n14) CEU32(n7,n15) \
 CEU32(n0,n4) CEU32(n1,n5) CEU32(n2,n6) CEU32(n3,n7) CEU32(n8,n12) CEU32(n9,n13) CEU32(n10,n14) CEU32(n11,n15) \
 CEU32(n0,n2) CEU32(n1,n3) CEU32(n4,n6) CEU32(n5,n7) CEU32(n8,n10) CEU32(n9,n11) CEU32(n12,n14) CEU32(n13,n15) \
 CEU32(n0,n1) CEU32(n2,n3) CEU32(n4,n5) CEU32(n6,n7) CEU32(n8,n9) CEU32(n10,n11) CEU32(n12,n13) CEU32(n14,n15)

#define MRGU(mm) do{ \
    u32 p0 =(u32)__shfl_xor((int)kk15,mm), p1 =(u32)__shfl_xor((int)kk14,mm); \
    u32 p2 =(u32)__shfl_xor((int)kk13,mm), p3 =(u32)__shfl_xor((int)kk12,mm); \
    u32 p4 =(u32)__shfl_xor((int)kk11,mm), p5 =(u32)__shfl_xor((int)kk10,mm); \
    u32 p6 =(u32)__shfl_xor((int)kk9, mm), p7 =(u32)__shfl_xor((int)kk8, mm); \
    u32 p8 =(u32)__shfl_xor((int)kk7, mm), p9 =(u32)__shfl_xor((int)kk6, mm); \
    u32 p10=(u32)__shfl_xor((int)kk5, mm), p11=(u32)__shfl_xor((int)kk4, mm); \
    u32 p12=(u32)__shfl_xor((int)kk3, mm), p13=(u32)__shfl_xor((int)kk2, mm); \
    u32 p14=(u32)__shfl_xor((int)kk1, mm), p15=(u32)__shfl_xor((int)kk0, mm); \
    kk0 =UMIN(kk0 ,p0 ); kk1 =UMIN(kk1 ,p1 ); kk2 =UMIN(kk2 ,p2 ); kk3 =UMIN(kk3 ,p3 ); \
    kk4 =UMIN(kk4 ,p4 ); kk5 =UMIN(kk5 ,p5 ); kk6 =UMIN(kk6 ,p6 ); kk7 =UMIN(kk7 ,p7 ); \
    kk8 =UMIN(kk8 ,p8 ); kk9 =UMIN(kk9 ,p9 ); kk10=UMIN(kk10,p10); kk11=UMIN(kk11,p11); \
    kk12=UMIN(kk12,p12); kk13=UMIN(kk13,p13); kk14=UMIN(kk14,p14); kk15=UMIN(kk15,p15); \
    M16U(kk0,kk1,kk2,kk3,kk4,kk5,kk6,kk7,kk8,kk9,kk10,kk11,kk12,kk13,kk14,kk15) \
}while(0)

#define OUTE8(e, kv) if (((e) & 7) == r) { \
    int _j = (int)((kv) & 1023u); \
    float4 _sj = s4[_j]; \
    float _dx = si.x-_sj.x, _dy = si.y-_sj.y, _dz = si.z-_sj.z, _dw = si.w-_sj.w; \
    float _d2 = _dx*_dx + _dy*_dy + _dz*_dz + _dw*_dw; \
    ew_out[bq + (e)] = expf(-10.0f * _d2); \
    idx_out[bq + (e)] = gbase + _j; }

// ---------------------------------------------------------------------------
// Kernel 2 v6b: exact kNN (K=16), med3-insert. gofs = graph offset so the
// launch can be split into two half-dispatches (diagnostic visibility).
// ---------------------------------------------------------------------------
__global__ __launch_bounds__(256) void k2_knn(
    const float* __restrict__ s, int* __restrict__ idx_out, float* __restrict__ ew_out,
    int gofs)
{
    __shared__ float4 s4[NPG];
    int tid = threadIdx.x;
    int g     = (blockIdx.x >> 5) + gofs;
    int gbase = g * NPG;
    int qblk  = (blockIdx.x & 31) * 32;
    const float4* sg = (const float4*)(s + (size_t)g*NPG*SPACE);
    for (int e = tid; e < NPG; e += 256) s4[e] = sg[e];
    __syncthreads();

    int lane = tid & 63;
    int grp  = lane >> 3;                   // 8 queries per wave
    int r    = lane & 7;                    // candidate octant
    int q    = qblk + (tid >> 6)*8 + grp;
    float4 si = s4[q];

    u32 kk0=~0u,kk1=~0u,kk2=~0u,kk3=~0u,kk4=~0u,kk5=~0u,kk6=~0u,kk7=~0u,
        kk8=~0u,kk9=~0u,kk10=~0u,kk11=~0u,kk12=~0u,kk13=~0u,kk14=~0u,kk15=~0u;

    int jb0 = r*128;
    #pragma unroll 2
    for (int it = 0; it < 128; ++it) {
        int j = jb0 + ((it + 3*r) & 127);   // 8 distinct banks per wave-instr
        float4 sj = s4[j];
        float dx = si.x-sj.x, dy = si.y-sj.y, dz = si.z-sj.z, dw = si.w-sj.w;
        float d2 = dx*dx + dy*dy + dz*dz + dw*dw;
        u32 key = (__float_as_uint(d2) & ~1023u) | (u32)j;
        key = (j == q) ? ~0u : key;         // exclude self
        INS16(key);
    }

    MRGU(1); MRGU(2); MRGU(4);              // merge 8 octant-top16s

    size_t bq = ((size_t)(gbase + q)) * KNN;
    OUTE8(0,kk0)  OUTE8(1,kk1)  OUTE8(2,kk2)   OUTE8(3,kk3)
    OUTE8(4,kk4)  OUTE8(5,kk5)  OUTE8(6,kk6)   OUTE8(7,kk7)
    OUTE8(8,kk8)  OUTE8(9,kk9)  OUTE8(10,kk10) OUTE8(11,kk11)
    OUTE8(12,kk12) OUTE8(13,kk13) OUTE8(14,kk14) OUTE8(15,kk15)
}

// ---------------------------------------------------------------------------
typedef __attribute__((ext_vector_type(8))) short bf16x8;
typedef __attribute__((ext_vector_type(4))) float f32x4;

// ---------------------------------------------------------------------------
// Kernel 3: standalone aggregation, wave-per-node, no LDS -> full occupancy.
// Writes agg as bf16 row-major [N][256].
// ---------------------------------------------------------------------------
__global__ __launch_bounds__(256) void k3_agg(
    const float* __restrict__ h, const float* __restrict__ z,
    const int* __restrict__ idx, const float* __restrict__ ew,
    u16* __restrict__ agg16)
{
    int tid = threadIdx.x;
    int lane = tid & 63;
    int i = blockIdx.x*4 + (tid >> 6);
    float zi = z[i];

    int   kq = lane & 15;
    int   jv = idx[(size_t)i*KNN + kq];
    float ev = ew[(size_t)i*KNN + kq];
    float dz = z[jv] - zi;
    float as = fabsf(dz);
    as += __shfl_xor(as, 1); as += __shfl_xor(as, 2);
    as += __shfl_xor(as, 4); as += __shfl_xor(as, 8);
    float F = dz / (as + 1e-8f);

    float mean = 0.f, mx = -INFINITY, sm = 0.f, dv = 0.f;
    #pragma unroll
    for (int k = 0; k < KNN; ++k) {
        int   j = __shfl(jv, k);
        float e = __shfl(ev, k);
        float f = __shfl(F,  k);
        float hv = h[(size_t)j*PROP + lane];   // 256B coalesced, L2-resident
        float m = hv * e;
        mean += m; mx = fmaxf(mx, m);
        sm += m * fabsf(f); dv += m * f;
    }
    u16* ap = agg16 + (size_t)i*256;
    ap[lane]       = bfr(mean * 0.0625f);
    ap[64 + lane]  = bfr(mx);
    ap[128 + lane] = bfr(sm * 0.0625f);
    ap[192 + lane] = bfr(dv);
}

// ---------------------------------------------------------------------------
// Kernel 4 v4: pure GEMM, all operands pre-converted bf16 -> staging is
// uint4 copies only. BM=64, BN=128, 5 K-chunks. 25KB LDS -> 6 blocks/CU.
// ---------------------------------------------------------------------------
__global__ __launch_bounds__(256) void k4_gemm(
    const u16* __restrict__ x16, const u16* __restrict__ agg16,
    const u16* __restrict__ wsk16, const u16* __restrict__ wag16,
    const float* __restrict__ bagg, float* __restrict__ out,
    float* __restrict__ partial)
{
    __shared__ char Atl[64*128];    // 8KB  [row][64ch] bf16, swizzled
    __shared__ char Bl[128*128];    // 16KB [n][64ch]  bf16, swizzled
    __shared__ float st[128], st2[128];
    int tid = threadIdx.x;
    int lane = tid & 63, wid = tid >> 6;
    int bid = blockIdx.x;
    int mbase = bid * 64;

    if (tid < 128) { st[tid] = 0.f; st2[tid] = 0.f; }

    int wy = wid >> 1, wx = wid & 1;
    int colb = wx*64 + (lane & 15);
    f32x4 acc[2][4];
    #pragma unroll
    for (int nc = 0; nc < 4; ++nc) {
        float bv = bagg[colb + nc*16];
        #pragma unroll
        for (int mr = 0; mr < 2; ++mr) acc[mr][nc] = (f32x4){bv, bv, bv, bv};
    }

    int arow = tid >> 2, aseg = (tid & 3) * 16;    // A: 16 u16 per thread
    int asw  = (arow & 7) << 4;
    int brow = tid >> 1, bkq = (tid & 1) * 32;     // B: 32 u16 per thread
    int bsw  = (brow & 7) << 4;

    for (int ch = 0; ch < 5; ++ch) {
        __syncthreads();   // previous chunk's tile reads done
        {
            const u16* ap = (ch == 0)
                ? (x16   + (size_t)(mbase + arow)*64  + aseg)
                : (agg16 + (size_t)(mbase + arow)*256 + (ch-1)*64 + aseg);
            uint4 u0 = ((const uint4*)ap)[0];
            uint4 u1 = ((const uint4*)ap)[1];
            *(uint4*)(Atl + arow*128 + ((aseg*2     ) ^ asw)) = u0;
            *(uint4*)(Atl + arow*128 + ((aseg*2 + 16) ^ asw)) = u1;
        }
        {
            const u16* bp = (ch == 0)
                ? (wsk16 + (size_t)brow*64  + bkq)
                : (wag16 + (size_t)brow*256 + (ch-1)*64 + bkq);
            #pragma unroll
            for (int g2 = 0; g2 < 4; ++g2) {
                uint4 u = ((const uint4*)bp)[g2];
                *(uint4*)(Bl + brow*128 + ((bkq*2 + g2*16) ^ bsw)) = u;
            }
        }
        __syncthreads();

        #pragma unroll
        for (int ks = 0; ks < 2; ++ks) {
            int kb = ks*64 + ((lane >> 4) * 16);   // byte offset in 128B row
            bf16x8 af[2], bfrg[4];
            #pragma unroll
            for (int mr = 0; mr < 2; ++mr) {
                int row = wy*32 + mr*16 + (lane & 15);
                af[mr] = *(const bf16x8*)(Atl + row*128 + (kb ^ ((row & 7) << 4)));
            }
            #pragma unroll
            for (int nc = 0; nc < 4; ++nc) {
                int n = wx*64 + nc*16 + (lane & 15);
                bfrg[nc] = *(const bf16x8*)(Bl + n*128 + (kb ^ ((n & 7) << 4)));
            }
            #pragma unroll
            for (int mr = 0; mr < 2; ++mr)
                #pragma unroll
                for (int nc = 0; nc < 4; ++nc)
                    acc[mr][nc] = __builtin_amdgcn_mfma_f32_16x16x32_bf16(
                        af[mr], bfrg[nc], acc[mr][nc], 0, 0, 0);
        }
    }

    // ---- epilogue: store + per-channel BN partial stats ----
    float s1[4] = {0,0,0,0}, s2[4] = {0,0,0,0};
    #pragma unroll
    for (int mr = 0; mr < 2; ++mr) {
        int r0 = mbase + wy*32 + mr*16 + (lane >> 4)*4;
        #pragma unroll
        for (int nc = 0; nc < 4; ++nc) {
            int c = colb + nc*16;
            #pragma unroll
            for (int j = 0; j < 4; ++j) {
                float v = acc[mr][nc][j];
                out[(size_t)(r0 + j)*OUT_CH + c] = v;
                s1[nc] += v;
                s2[nc] += v*v;
            }
        }
    }
    #pragma unroll
    for (int nc = 0; nc < 4; ++nc) {
        s1[nc] += __shfl_xor(s1[nc], 16); s1[nc] += __shfl_xor(s1[nc], 32);
        s2[nc] += __shfl_xor(s2[nc], 16); s2[nc] += __shfl_xor(s2[nc], 32);
    }
    __syncthreads();
    if ((lane >> 4) == 0) {
        #pragma unroll
        for (int nc = 0; nc < 4; ++nc) {
            atomicAdd(&st[colb + nc*16],  s1[nc]);
            atomicAdd(&st2[colb + nc*16], s2[nc]);
        }
    }
    __syncthreads();
    if (tid < 128) {
        partial[(size_t)bid*256 + tid]       = st[tid];
        partial[(size_t)bid*256 + 128 + tid] = st2[tid];
    }
}

// ---------------------------------------------------------------------------
// Kernel 5r: reduce 1024 block-partials -> sums[256] (sums pre-zeroed by k1)
// ---------------------------------------------------------------------------
__global__ __launch_bounds__(256) void k5_red(
    const float* __restrict__ partial, float* __restrict__ sums)
{
    int c = threadIdx.x;
    int b0 = blockIdx.x * 32;
    float acc = 0.f;
    #pragma unroll 8
    for (int b = 0; b < 32; ++b)
        acc += partial[(size_t)(b0 + b)*256 + c];
    atomicAdd(&sums[c], acc);
}

// ---------------------------------------------------------------------------
// Kernel 6: BatchNorm (training stats, biased var) + ReLU, in place on d_out
// ---------------------------------------------------------------------------
__global__ __launch_bounds__(256) void k6_bn(
    float* __restrict__ out, const float* __restrict__ sums,
    const float* __restrict__ gamma, const float* __restrict__ beta)
{
    int f = blockIdx.x*256 + threadIdx.x;     // float4 index
    float4 v = *(float4*)(out + (size_t)f*4);
    int o0 = (f*4) & 127;
    const float invN = 1.f / (float)NTOT;
    float r[4] = {v.x, v.y, v.z, v.w};
    #pragma unroll
    for (int c = 0; c < 4; c++) {
        int o = o0 + c;
        float mu  = sums[o] * invN;
        float var = sums[128+o] * invN - mu*mu;
        float sc  = gamma[o] * rsqrtf(var + 1e-5f);
        float sh  = beta[o] - mu*sc;
        float y = r[c]*sc + sh;
        r[c] = y > 0.f ? y : 0.f;
    }
    *(float4*)(out + (size_t)f*4) = make_float4(r[0], r[1], r[2], r[3]);
}

// ---------------------------------------------------------------------------
extern "C" void kernel_launch(void* const* d_in, const int* in_sizes, int n_in,
                              void* d_out, int out_size, void* d_ws, size_t ws_size,
                              hipStream_t stream)
{
    (void)in_sizes; (void)n_in; (void)out_size; (void)ws_size;
    const float* x     = (const float*)d_in[0];
    const float* z     = (const float*)d_in[1];
    /* d_in[2] = batch (int32) — graphs are fixed contiguous blocks, unused */
    const float* Ws    = (const float*)d_in[3];
    const float* bs    = (const float*)d_in[4];
    const float* Wh    = (const float*)d_in[5];
    const float* bh    = (const float*)d_in[6];
    const float* Wskip = (const float*)d_in[7];
    const float* Wagg  = (const float*)d_in[8];
    const float* bagg  = (const float*)d_in[9];
    const float* gamma = (const float*)d_in[10];
    const float* beta  = (const float*)d_in[11];
    float* out = (float*)d_out;

    const size_t N = NTOT;
    float* ws    = (float*)d_ws;
    float* sbuf  = ws;                           // N*4 f32
    float* hbuf  = sbuf + N*4;                   // N*64 f32
    int*   idxb  = (int*)(hbuf + N*64);          // N*16 int32
    float* ewb   = (float*)(idxb + N*16);        // N*16 f32
    u16*   agg16 = (u16*)(ewb + N*16);           // N*256 u16
    u16*   x16   = agg16 + (size_t)N*256;        // N*64 u16
    u16*   wsk16 = x16 + (size_t)N*64;           // 8192 u16
    u16*   wag16 = wsk16 + OUT_CH*IN_CH;         // 32768 u16
    float* part  = (float*)(wag16 + OUT_CH*4*PROP); // 1024*256 f32
    float* sums  = part + 1024*256;              // 256 f32

    k1_proj<<<NTOT/256 + 2, 256, 0, stream>>>(x, Ws, bs, Wh, bh, Wskip, Wagg,
                                              sbuf, hbuf, x16, wsk16, wag16, sums);
    k2_knn <<<NGRAPH*16, 256, 0, stream>>>(sbuf, idxb, ewb, 0);
    k2_knn <<<NGRAPH*16, 256, 0, stream>>>(sbuf, idxb, ewb, NGRAPH/2);
    k3_agg <<<NTOT/4,   256, 0, stream>>>(hbuf, z, idxb, ewb, agg16);
    k4_gemm<<<NTOT/64,  256, 0, stream>>>(x16, agg16, wsk16, wag16, bagg, out, part);
    k5_red <<<32, 256, 0, stream>>>(part, sums);
    k6_bn  <<<NTOT*OUT_CH/4/256, 256, 0, stream>>>(out, sums, gamma, beta);
}